// Round 5
// baseline (686.530 us; speedup 1.0000x reference)
//
#include <hip/hip_runtime.h>
#include <stdint.h>
#include <stddef.h>

#define BATCH 512
#define NQ    65536
#define DIM   768
#define DIM2  1536

typedef __attribute__((ext_vector_type(4))) float f32x4;
typedef __attribute__((ext_vector_type(4))) unsigned short u16x4;
typedef __attribute__((ext_vector_type(8))) unsigned short u16x8;
typedef __attribute__((ext_vector_type(8))) __bf16 bf16x8;

// ---------- fp32 <-> bf16 (round-to-nearest-even) ----------
static __device__ __forceinline__ unsigned short f2bf(float x){
    unsigned int u = __float_as_uint(x);
    unsigned int r = ((u >> 16) & 1u) + 0x7fffu;
    return (unsigned short)((u + r) >> 16);
}
static __device__ __forceinline__ float bf2f(unsigned short h){
    return __uint_as_float(((unsigned int)h) << 16);
}

// ---------- top-2 tracking ----------
struct T2 { float v1, v2; int i1, i2; };
static __device__ __forceinline__ void t2_add(T2& t, float v, int i){
    if (v > t.v1 || (v == t.v1 && i < t.i1)) { t.v2 = t.v1; t.i2 = t.i1; t.v1 = v; t.i1 = i; }
    else if (v > t.v2 || (v == t.v2 && i < t.i2)) { t.v2 = v; t.i2 = i; }
}
static __device__ __forceinline__ T2 t2_init(){ T2 t; t.v1 = -3.4e38f; t.v2 = -3.4e38f; t.i1 = 0x7fffffff; t.i2 = 0x7fffffff; return t; }

// ---------- prep: L2-normalize features, split to bf16 hi/lo, seed queue rows ----------
__global__ __launch_bounds__(256) void prep_kernel(
    const float* __restrict__ img, const float* __restrict__ txt,
    float* __restrict__ img_f, float* __restrict__ txt_f,
    unsigned short* __restrict__ X2hi, unsigned short* __restrict__ X2lo,
    unsigned short* __restrict__ X1hi, unsigned short* __restrict__ X1lo,
    float* __restrict__ out2, float* __restrict__ out3)
{
    int b = blockIdx.x;
    bool isimg = (b < BATCH);
    int row = isimg ? b : b - BATCH;
    const float* src = (isimg ? img : txt) + (size_t)row * DIM;
    float v[3];
    float ss = 0.f;
    #pragma unroll
    for (int i = 0; i < 3; i++){ v[i] = src[threadIdx.x + i*256]; ss += v[i]*v[i]; }
    #pragma unroll
    for (int m = 1; m < 64; m <<= 1) ss += __shfl_xor(ss, m);
    __shared__ float red[4];
    if ((threadIdx.x & 63) == 0) red[threadIdx.x >> 6] = ss;
    __syncthreads();
    float tot = red[0] + red[1] + red[2] + red[3];
    float scale = 1.0f / fmaxf(sqrtf(tot), 1e-12f);
    float* fdst = (isimg ? img_f : txt_f) + (size_t)row * DIM;
    float* odst = (isimg ? out2  : out3 ) + (size_t)row * DIM;
    unsigned short* hid = (isimg ? X2hi : X1hi) + (size_t)row * DIM2;
    unsigned short* lod = (isimg ? X2lo : X1lo) + (size_t)row * DIM2;
    #pragma unroll
    for (int i = 0; i < 3; i++){
        int c = threadIdx.x + i*256;
        float y = v[i] * scale;
        fdst[c] = y; odst[c] = y;
        unsigned short h = f2bf(y);
        hid[c] = h; lod[c] = f2bf(y - bf2f(h));
    }
}

// ---------- transpose W [1536][768] -> Wt [768][1536] (fp32) ----------
__global__ __launch_bounds__(256) void transpose_kernel(
    const float* __restrict__ Wd, const float* __restrict__ Wc,
    float* __restrict__ Td, float* __restrict__ Tc)
{
    __shared__ float t[32][33];
    const float* W = blockIdx.z ? Wc : Wd;
    float*       T = blockIdx.z ? Tc : Td;
    int x0 = blockIdx.x * 32;
    int y0 = blockIdx.y * 32;
    int tx = threadIdx.x & 31, ty = threadIdx.x >> 5;
    #pragma unroll
    for (int i = 0; i < 32; i += 8)
        t[ty + i][tx] = W[(size_t)(y0 + ty + i) * DIM + x0 + tx];
    __syncthreads();
    #pragma unroll
    for (int i = 0; i < 32; i += 8)
        T[(size_t)(x0 + ty + i) * DIM2 + y0 + tx] = t[tx][ty + i];
}

#define EPI_TOP2      0
#define EPI_BIAS_RELU 1
#define EPI_BIAS      2
#define EPI_SCALE     3

// ---------- fused big GEMM: C = A * B^T ----------
// A: pre-split bf16 hi/lo (workspace), staged via global_load_lds (pre-swizzled source).
// B: fp32 queue read directly; reg-staged -> f2bf hi/lo -> swizzled ds_write; the fp32
//    values are written through to new_queue (rows >= BATCH, mb==0 blocks only).
// 128x128 tile, 4 waves (2x2), per-wave 64x64, 64 KiB LDS -> 2 blocks/CU.
// LDS rows: 128B = 8 granules of 16B, granule-XOR (row&7) swizzle.
// NTERMS==3: KS=32, row=[hi k0..31 | lo k0..31], 3 MFMA/frag-pair (split-bf16).
// NTERMS==2: KS=64, row=[hi k0..31 | hi k32..63] (pass Alo=Ahi+32), plain bf16.
template<int NTERMS, int EPI>
__global__ __launch_bounds__(256, 2) void gemm_fused(
    const unsigned short* __restrict__ Ahi, const unsigned short* __restrict__ Alo, int lda,
    const float* __restrict__ B, int ldb, int K, int Nout,
    float* __restrict__ wt_out,
    float* __restrict__ outp, const float* __restrict__ scale_ptr, int Mtot)
{
    constexpr int BM = 128, BN = 128, NT = 256;
    constexpr int ABYTES = BM * 128, BBYTES = BN * 128, BUF = ABYTES + BBYTES; // 32 KiB
    constexpr int KS  = (NTERMS == 3) ? 32 : 64;
    constexpr int NBV = KS / 8;              // f32x4 regs per thread for B staging
    __shared__ __align__(16) char lds[2 * BUF];   // 64 KiB

    const int tid = threadIdx.x, lane = tid & 63, wid = tid >> 6;
    const int wm = wid >> 1, wn = wid & 1;
    const int lr = lane & 15, lg = lane >> 4;
    // chunked XCD swizzle: grid 2048 = 512 nb x 4 mb; each XCD gets a contiguous
    // l-range so the 4 mb-blocks of one nb share that XCD's L2 (B-tile reuse).
    const int id = blockIdx.x;
    const int l  = (id & 7) * 256 + (id >> 3);
    const int nb = l >> 2, mb = l & 3;
    const int m0 = mb * BM, n0 = nb * BN;

    f32x4 acc[4][4] = {};
    f32x4 bv[NBV];
    const int brow = tid >> 1, bhalf = tid & 1;
    const int brw7 = brow & 7;

    auto stageA = [&](int buf, int k0){
        char* base = lds + buf * BUF;
        #pragma unroll
        for (int r = 0; r < 4; r++){
            int G = r * NT + tid, row = G >> 3, slot = G & 7, s0 = slot ^ (row & 7);
            const unsigned short* s = ((s0 < 4) ? Ahi : Alo) + (size_t)(m0 + row) * lda + k0 + (s0 & 3) * 8;
            __builtin_amdgcn_global_load_lds(
                (const __attribute__((address_space(1))) void*)s,
                (__attribute__((address_space(3))) void*)(base + (r * NT + (tid & ~63)) * 16), 16, 0, 0);
        }
    };
    auto loadB = [&](int kt){
        const float* bp = B + (size_t)(n0 + brow) * ldb + kt * KS + bhalf * (KS / 2);
        #pragma unroll
        for (int i = 0; i < NBV; i++) bv[i] = ((const f32x4*)bp)[i];
    };
    auto writeB = [&](int buf, int kt){
        // fp32 passthrough to new_queue (exact copy; rows < BATCH owned by prep)
        if (mb == 0 && (n0 + brow) >= BATCH){
            float* wp = wt_out + (size_t)(n0 + brow) * ldb + kt * KS + bhalf * (KS / 2);
            #pragma unroll
            for (int i = 0; i < NBV; i++) ((f32x4*)wp)[i] = bv[i];
        }
        char* bb = lds + buf * BUF + ABYTES + brow * 128;
        if (NTERMS == 3){
            u16x8 h[2], lo2[2];
            #pragma unroll
            for (int p = 0; p < 2; p++)
            #pragma unroll
            for (int j = 0; j < 8; j++){
                float x = bv[p * 2 + (j >> 2)][j & 3];
                unsigned short hh = f2bf(x);
                h[p][j] = hh; lo2[p][j] = f2bf(x - bf2f(hh));
            }
            #pragma unroll
            for (int p = 0; p < 2; p++){
                *(u16x8*)(bb + (((bhalf * 2 + p)    ) ^ brw7) * 16) = h[p];
                *(u16x8*)(bb + (((bhalf * 2 + p) + 4) ^ brw7) * 16) = lo2[p];
            }
        } else {
            u16x8 h[4];
            #pragma unroll
            for (int p = 0; p < 4; p++)
            #pragma unroll
            for (int j = 0; j < 8; j++)
                h[p][j] = f2bf(bv[p * 2 + (j >> 2)][j & 3]);
            #pragma unroll
            for (int p = 0; p < 4; p++)
                *(u16x8*)(bb + ((bhalf * 4 + p) ^ brw7) * 16) = h[p];
        }
    };
    auto compute = [&](int buf){
        const char* Ab = lds + buf * BUF;
        const char* Bb = Ab + ABYTES;
        bf16x8 ah[4], al[4], bh[4], bl[4];
        #pragma unroll
        for (int f = 0; f < 4; f++){
            int rowa = wm * 64 + f * 16 + lr;
            const char* rpa = Ab + rowa * 128;
            ah[f] = *(const bf16x8*)(rpa + ((lg ^ (rowa & 7)) << 4));
            al[f] = *(const bf16x8*)(rpa + (((4 + lg) ^ (rowa & 7)) << 4));
            int rowb = wn * 64 + f * 16 + lr;
            const char* rpb = Bb + rowb * 128;
            bh[f] = *(const bf16x8*)(rpb + ((lg ^ (rowb & 7)) << 4));
            bl[f] = *(const bf16x8*)(rpb + (((4 + lg) ^ (rowb & 7)) << 4));
        }
        #pragma unroll
        for (int mf = 0; mf < 4; mf++)
        #pragma unroll
        for (int nf = 0; nf < 4; nf++){
            if (NTERMS == 3){
                acc[mf][nf] = __builtin_amdgcn_mfma_f32_16x16x32_bf16(ah[mf], bh[nf], acc[mf][nf], 0, 0, 0);
                acc[mf][nf] = __builtin_amdgcn_mfma_f32_16x16x32_bf16(al[mf], bh[nf], acc[mf][nf], 0, 0, 0);
                acc[mf][nf] = __builtin_amdgcn_mfma_f32_16x16x32_bf16(ah[mf], bl[nf], acc[mf][nf], 0, 0, 0);
            } else {
                acc[mf][nf] = __builtin_amdgcn_mfma_f32_16x16x32_bf16(ah[mf], bh[nf], acc[mf][nf], 0, 0, 0);
                acc[mf][nf] = __builtin_amdgcn_mfma_f32_16x16x32_bf16(al[mf], bl[nf], acc[mf][nf], 0, 0, 0);
            }
        }
    };

    stageA(0, 0); loadB(0); writeB(0, 0);
    __syncthreads();
    const int nk = K / KS;
    int cur = 0;
    for (int kt = 0; kt < nk; kt++){
        if (kt + 1 < nk){ stageA(cur ^ 1, (kt + 1) * KS); loadB(kt + 1); }
        compute(cur);
        if (kt + 1 < nk) writeB(cur ^ 1, kt + 1);
        __syncthreads();
        cur ^= 1;
    }

    if constexpr (EPI == EPI_TOP2){
        T2* t2l = (T2*)lds;   // [2][128]
        #pragma unroll
        for (int mf = 0; mf < 4; mf++){
            #pragma unroll
            for (int r = 0; r < 4; r++){
                T2 t = t2_init();
                #pragma unroll
                for (int nf = 0; nf < 4; nf++){
                    int gc = n0 + wn * 64 + nf * 16 + lr;
                    t2_add(t, acc[mf][nf][r], gc);
                }
                #pragma unroll
                for (int m = 1; m < 16; m <<= 1){
                    float ov1 = __shfl_xor(t.v1, m), ov2 = __shfl_xor(t.v2, m);
                    int   oi1 = __shfl_xor(t.i1, m), oi2 = __shfl_xor(t.i2, m);
                    t2_add(t, ov1, oi1); t2_add(t, ov2, oi2);
                }
                if (lr == 0){
                    int rowit = wm * 64 + mf * 16 + lg * 4 + r;
                    t2l[wn * 128 + rowit] = t;
                }
            }
        }
        __syncthreads();
        if (tid < 128){
            T2 t = t2l[tid];
            T2 o = t2l[128 + tid];
            t2_add(t, o.v1, o.i1); t2_add(t, o.v2, o.i2);
            f32x4 pk; pk[0] = t.v1; pk[1] = __int_as_float(t.i1); pk[2] = t.v2; pk[3] = __int_as_float(t.i2);
            ((f32x4*)outp)[(size_t)nb * Mtot + (m0 + tid)] = pk;
        }
    } else if constexpr (EPI == EPI_SCALE){
        float sc = scale_ptr[0];
        #pragma unroll
        for (int mf = 0; mf < 4; mf++)
        #pragma unroll
        for (int nf = 0; nf < 4; nf++)
        #pragma unroll
        for (int r = 0; r < 4; r++){
            int grow = m0 + wm * 64 + mf * 16 + lg * 4 + r;
            int gcol = n0 + wn * 64 + nf * 16 + lr;
            outp[(size_t)grow * Nout + gcol] = acc[mf][nf][r] * sc;
        }
    }
}

// ---------- small GEMM (MLP layers): A bf16 hi/lo, B fp32 with in-kernel convert ----------
template<int BM,int BN,int WGM,int WGN,int EPI>
__global__ __launch_bounds__(WGM*WGN*64) void gemm_small(
    const unsigned short* __restrict__ Ahi, const unsigned short* __restrict__ Alo, int lda,
    const float* __restrict__ B, int ldb, int K,
    const float* __restrict__ bias,
    unsigned short* __restrict__ dsthi, unsigned short* __restrict__ dstlo, int ldd, int dstoff)
{
    constexpr int WM = BM / WGM, WN = BN / WGN;
    constexpr int MF = WM / 16, NF = WN / 16;
    constexpr int NT = WGM * WGN * 64;
    constexpr int ABYTES = BM * 128;
    constexpr int BBYTES = BN * 128;
    constexpr int BUF = ABYTES + BBYTES;
    static_assert(BN * 4 == NT, "");
    static_assert((BM * 8) % NT == 0, "");

    __shared__ __align__(16) char lds[2 * BUF];

    const int tid  = threadIdx.x;
    const int wid  = tid >> 6, lane = tid & 63;
    const int wm   = wid / WGN, wn = wid % WGN;
    const int lr   = lane & 15, lg = lane >> 4;
    const int nb   = blockIdx.x, mb = blockIdx.y;
    const int m0   = mb * BM, n0 = nb * BN;

    f32x4 acc[MF][NF] = {};
    f32x4 breg0, breg1;

    auto stageA = [&](int buf, int k0){
        char* base = lds + buf * BUF;
        constexpr int RA = BM * 8 / NT;
        #pragma unroll
        for (int r = 0; r < RA; r++){
            int G = r * NT + tid;
            int row = G >> 3, slot = G & 7;
            int s0 = slot ^ (row & 7);
            const unsigned short* src = ((s0 < 4) ? Ahi : Alo)
                + (size_t)(m0 + row) * lda + (k0 + (s0 & 3) * 8);
            char* ldst = base + r * NT * 16 + (tid & ~63) * 16;
            __builtin_amdgcn_global_load_lds(
                (const __attribute__((address_space(1))) void*)src,
                (__attribute__((address_space(3))) void*)ldst, 16, 0, 0);
        }
    };
    auto loadB = [&](int kt){
        int k0 = kt * 32;
        int row = tid >> 2, quad = tid & 3;
        const float* bp = B + (size_t)(n0 + row) * ldb + k0 + quad * 8;
        breg0 = *(const f32x4*)bp;
        breg1 = *(const f32x4*)(bp + 4);
    };
    auto writeB = [&](int buf){
        char* base = lds + buf * BUF + ABYTES;
        int row = tid >> 2, quad = tid & 3;
        u16x8 h8, l8;
        #pragma unroll
        for (int j = 0; j < 8; j++){
            float x = (j < 4) ? breg0[j] : breg1[j - 4];
            unsigned short h = f2bf(x);
            h8[j] = h; l8[j] = f2bf(x - bf2f(h));
        }
        int sh = quad ^ (row & 7), sl = (4 + quad) ^ (row & 7);
        *(u16x8*)(base + row * 128 + sh * 16) = h8;
        *(u16x8*)(base + row * 128 + sl * 16) = l8;
    };
    auto compute = [&](int buf){
        const char* Ab = lds + buf * BUF;
        const char* Bb = Ab + ABYTES;
        bf16x8 ah[MF], al[MF], bh[NF], bl[NF];
        #pragma unroll
        for (int mf = 0; mf < MF; mf++){
            int row = wm * WM + mf * 16 + lr;
            const char* rp = Ab + row * 128;
            ah[mf] = *(const bf16x8*)(rp + ((lg ^ (row & 7)) << 4));
            al[mf] = *(const bf16x8*)(rp + (((4 + lg) ^ (row & 7)) << 4));
        }
        #pragma unroll
        for (int nf = 0; nf < NF; nf++){
            int row = wn * WN + nf * 16 + lr;
            const char* rp = Bb + row * 128;
            bh[nf] = *(const bf16x8*)(rp + ((lg ^ (row & 7)) << 4));
            bl[nf] = *(const bf16x8*)(rp + (((4 + lg) ^ (row & 7)) << 4));
        }
        #pragma unroll
        for (int mf = 0; mf < MF; mf++)
        #pragma unroll
        for (int nf = 0; nf < NF; nf++){
            acc[mf][nf] = __builtin_amdgcn_mfma_f32_16x16x32_bf16(ah[mf], bh[nf], acc[mf][nf], 0, 0, 0);
            acc[mf][nf] = __builtin_amdgcn_mfma_f32_16x16x32_bf16(al[mf], bh[nf], acc[mf][nf], 0, 0, 0);
            acc[mf][nf] = __builtin_amdgcn_mfma_f32_16x16x32_bf16(ah[mf], bl[nf], acc[mf][nf], 0, 0, 0);
        }
    };

    stageA(0, 0); loadB(0); writeB(0);
    __syncthreads();
    const int nk = K / 32;
    int cur = 0;
    for (int kt = 0; kt < nk; kt++){
        if (kt + 1 < nk){ stageA(cur ^ 1, (kt + 1) * 32); loadB(kt + 1); }
        compute(cur);
        if (kt + 1 < nk){ writeB(cur ^ 1); }
        __syncthreads();
        cur ^= 1;
    }

    #pragma unroll
    for (int mf = 0; mf < MF; mf++)
    #pragma unroll
    for (int nf = 0; nf < NF; nf++)
    #pragma unroll
    for (int r = 0; r < 4; r++){
        int grow = m0 + wm * WM + mf * 16 + lg * 4 + r;
        int gcol = n0 + wn * WN + nf * 16 + lr;
        float c = acc[mf][nf][r] + bias[gcol];
        if (EPI == EPI_BIAS_RELU) c = fmaxf(c, 0.f);
        unsigned short h = f2bf(c);
        size_t o = (size_t)grow * ldd + dstoff + gcol;
        dsthi[o] = h;
        dstlo[o] = f2bf(c - bf2f(h));
    }
}

// ---------- phase B: global top-2 merge + exact fp32 rescore -> argmax index ----------
__global__ __launch_bounds__(64) void phaseB_kernel(
    const f32x4* __restrict__ top2ws, int ntiles,
    const float* __restrict__ img_f, const float* __restrict__ qtxt,
    float* __restrict__ out_ind, int* __restrict__ ws_ind)
{
    int row = blockIdx.x;
    int lane = threadIdx.x;
    T2 t = t2_init();
    for (int j = lane; j < ntiles; j += 64){
        f32x4 e = top2ws[(size_t)j * BATCH + row];
        t2_add(t, e[0], __float_as_int(e[1]));
        t2_add(t, e[2], __float_as_int(e[3]));
    }
    #pragma unroll
    for (int m = 1; m < 64; m <<= 1){
        float ov1 = __shfl_xor(t.v1, m), ov2 = __shfl_xor(t.v2, m);
        int   oi1 = __shfl_xor(t.i1, m), oi2 = __shfl_xor(t.i2, m);
        t2_add(t, ov1, oi1); t2_add(t, ov2, oi2);
    }
    const float* a  = img_f + (size_t)row * DIM;
    const float* b1 = qtxt + (size_t)t.i1 * DIM;
    const float* b2 = qtxt + (size_t)t.i2 * DIM;
    float s1 = 0.f, s2 = 0.f;
    for (int c = lane; c < DIM; c += 64){ float av = a[c]; s1 += av * b1[c]; s2 += av * b2[c]; }
    #pragma unroll
    for (int m = 1; m < 64; m <<= 1){ s1 += __shfl_xor(s1, m); s2 += __shfl_xor(s2, m); }
    int ind = (s2 > s1 || (s2 == s1 && t.i2 < t.i1)) ? t.i2 : t.i1;
    if (lane == 0){ out_ind[row] = (float)ind; ws_ind[row] = ind; }
}

// ---------- gather t_similar rows into X1[:, 768:1536] as bf16 hi/lo ----------
__global__ __launch_bounds__(256) void gather_kernel(
    const int* __restrict__ ws_ind, const float* __restrict__ qtxt,
    unsigned short* __restrict__ X1hi, unsigned short* __restrict__ X1lo)
{
    int row = blockIdx.x;
    int ind = ws_ind[row];
    const float* src = qtxt + (size_t)ind * DIM;
    for (int c = threadIdx.x; c < DIM; c += 256){
        float x = src[c];
        unsigned short h = f2bf(x);
        X1hi[(size_t)row * DIM2 + DIM + c] = h;
        X1lo[(size_t)row * DIM2 + DIM + c] = f2bf(x - bf2f(h));
    }
}

extern "C" void kernel_launch(void* const* d_in, const int* in_sizes, int n_in,
                              void* d_out, int out_size, void* d_ws, size_t ws_size,
                              hipStream_t stream)
{
    (void)in_sizes; (void)n_in; (void)out_size; (void)ws_size;
    const float* img  = (const float*)d_in[0];
    const float* txt  = (const float*)d_in[1];
    const float* qimg = (const float*)d_in[2];
    const float* qtxt = (const float*)d_in[3];
    const float* Wd   = (const float*)d_in[4];
    const float* bd   = (const float*)d_in[5];
    const float* Wc   = (const float*)d_in[6];
    const float* bc   = (const float*)d_in[7];
    const float* ls   = (const float*)d_in[8];

    float* out0 = (float*)d_out;                    // logits [512][65536]
    float* out1 = out0 + (size_t)BATCH * NQ;        // ind_similar [512] (as f32)
    float* out2 = out1 + BATCH;                     // new_queue_img [65536][768]
    float* out3 = out2 + (size_t)NQ * DIM;          // new_queue_txt [65536][768]

    char* w = (char*)d_ws;
    auto alloc = [&](size_t bytes){ char* p = w; w += (bytes + 255) & ~(size_t)255; return p; };
    unsigned short* X1hi  = (unsigned short*)alloc((size_t)BATCH * DIM2 * 2);
    unsigned short* X1lo  = (unsigned short*)alloc((size_t)BATCH * DIM2 * 2);
    unsigned short* X2hi  = (unsigned short*)alloc((size_t)BATCH * DIM2 * 2);
    unsigned short* X2lo  = (unsigned short*)alloc((size_t)BATCH * DIM2 * 2);
    unsigned short* combhi= (unsigned short*)alloc((size_t)BATCH * DIM * 2);
    unsigned short* comblo= (unsigned short*)alloc((size_t)BATCH * DIM * 2);
    float* img_f  = (float*)alloc((size_t)BATCH * DIM * 4);
    float* txt_f  = (float*)alloc((size_t)BATCH * DIM * 4);
    float* Td     = (float*)alloc((size_t)DIM * DIM2 * 4);
    float* Tc     = (float*)alloc((size_t)DIM * DIM2 * 4);
    float* top2ws = (float*)alloc((size_t)(NQ / 128) * BATCH * 16);
    int*   ws_ind = (int*)alloc(BATCH * 4);

    // 1) normalize features, split to hi/lo, seed out2/out3 rows 0..511
    prep_kernel<<<dim3(2 * BATCH), dim3(256), 0, stream>>>(
        img, txt, img_f, txt_f, X2hi, X2lo, X1hi, X1lo, out2, out3);

    // 2) transpose weights to [768][1536] fp32
    transpose_kernel<<<dim3(DIM / 32, DIM2 / 32, 2), dim3(256), 0, stream>>>(Wd, Wc, Td, Tc);

    // 3) retrieval GEMM (split-bf16, fp32-B fused convert) + top2 + out3 write-through
    gemm_fused<3, EPI_TOP2><<<dim3(2048), dim3(256), 0, stream>>>(
        X2hi, X2lo, DIM2, qtxt, DIM, DIM, NQ, out3, top2ws, nullptr, BATCH);

    // 4) global top-2 + exact rescore -> ind_similar
    phaseB_kernel<<<dim3(BATCH), dim3(64), 0, stream>>>(
        (const f32x4*)top2ws, NQ / 128, img_f, qtxt, out1, ws_ind);

    // 5) gather t_similar into X1[:, 768:]
    gather_kernel<<<dim3(BATCH), dim3(256), 0, stream>>>(ws_ind, qtxt, X1hi, X1lo);

    // 6) diff = relu(X1 @ W_diff + b_diff) -> X2[:, 768:] (split)
    gemm_small<64,64,2,2,EPI_BIAS_RELU><<<dim3(DIM / 64, BATCH / 64), dim3(256), 0, stream>>>(
        X1hi, X1lo, DIM2, Td, DIM2, DIM2, bd, X2hi, X2lo, DIM2, DIM);

    // 7) combined = X2 @ W_comb + b_comb -> comb hi/lo
    gemm_small<64,64,2,2,EPI_BIAS><<<dim3(DIM / 64, BATCH / 64), dim3(256), 0, stream>>>(
        X2hi, X2lo, DIM2, Tc, DIM2, DIM2, bc, combhi, comblo, DIM, 0);

    // 8) logits = scale * combined @ queue_img^T (plain bf16 K64) + out2 write-through
    gemm_fused<2, EPI_SCALE><<<dim3(2048), dim3(256), 0, stream>>>(
        combhi, combhi + 32, DIM, qimg, DIM, DIM, NQ, out2, out0, ls, BATCH);
}

// Round 6
// 625.097 us; speedup vs baseline: 1.0983x; 1.0983x over previous
//
#include <hip/hip_runtime.h>
#include <stdint.h>
#include <stddef.h>

#define BATCH 512
#define NQ    65536
#define DIM   768
#define DIM2  1536

typedef __attribute__((ext_vector_type(4))) float f32x4;
typedef __attribute__((ext_vector_type(4))) unsigned short u16x4;
typedef __attribute__((ext_vector_type(8))) unsigned short u16x8;
typedef __attribute__((ext_vector_type(8))) __bf16 bf16x8;

// ---------- fp32 <-> bf16 (round-to-nearest-even) ----------
static __device__ __forceinline__ unsigned short f2bf(float x){
    unsigned int u = __float_as_uint(x);
    unsigned int r = ((u >> 16) & 1u) + 0x7fffu;
    return (unsigned short)((u + r) >> 16);
}
static __device__ __forceinline__ float bf2f(unsigned short h){
    return __uint_as_float(((unsigned int)h) << 16);
}

// ---------- top-2 tracking ----------
struct T2 { float v1, v2; int i1, i2; };
static __device__ __forceinline__ void t2_add(T2& t, float v, int i){
    if (v > t.v1 || (v == t.v1 && i < t.i1)) { t.v2 = t.v1; t.i2 = t.i1; t.v1 = v; t.i1 = i; }
    else if (v > t.v2 || (v == t.v2 && i < t.i2)) { t.v2 = v; t.i2 = i; }
}
static __device__ __forceinline__ T2 t2_init(){ T2 t; t.v1 = -3.4e38f; t.v2 = -3.4e38f; t.i1 = 0x7fffffff; t.i2 = 0x7fffffff; return t; }

// ---------- convert: queues fp32 -> bf16 hi/lo, fused new_queue passthrough ----------
// y==0: qtxt -> Bt_hi, Bt_lo, out3(copy).  y==1: qimg -> Bi_hi, out2(copy).
// prep_kernel runs AFTER this and overwrites out2/out3 rows 0..511 with normalized feats.
__global__ __launch_bounds__(256) void convert_kernel(
    const float* __restrict__ qtxt, const float* __restrict__ qimg,
    unsigned short* __restrict__ bthi, unsigned short* __restrict__ btlo,
    unsigned short* __restrict__ bihi,
    float* __restrict__ out3, float* __restrict__ out2)
{
    const bool isT = (blockIdx.y == 0);
    const float* __restrict__ src = isT ? qtxt : qimg;
    float* __restrict__ dst = isT ? out3 : out2;
    unsigned short* __restrict__ hi = isT ? bthi : bihi;
    unsigned short* __restrict__ lo = btlo;
    const size_t n4 = (size_t)NQ * DIM / 4;
    for (size_t i = (size_t)blockIdx.x * 256 + threadIdx.x; i < n4; i += (size_t)gridDim.x * 256) {
        f32x4 v = ((const f32x4*)src)[i];
        ((f32x4*)dst)[i] = v;
        u16x4 h, l;
        #pragma unroll
        for (int j = 0; j < 4; j++){
            unsigned short hh = f2bf(v[j]);
            h[j] = hh; l[j] = f2bf(v[j] - bf2f(hh));
        }
        *(u16x4*)(hi + 4*i) = h;
        if (isT) *(u16x4*)(lo + 4*i) = l;
    }
}

// ---------- prep: L2-normalize features, split to bf16 hi/lo, seed queue rows ----------
__global__ __launch_bounds__(256) void prep_kernel(
    const float* __restrict__ img, const float* __restrict__ txt,
    float* __restrict__ img_f, float* __restrict__ txt_f,
    unsigned short* __restrict__ X2hi, unsigned short* __restrict__ X2lo,
    unsigned short* __restrict__ X1hi, unsigned short* __restrict__ X1lo,
    float* __restrict__ out2, float* __restrict__ out3)
{
    int b = blockIdx.x;
    bool isimg = (b < BATCH);
    int row = isimg ? b : b - BATCH;
    const float* src = (isimg ? img : txt) + (size_t)row * DIM;
    float v[3];
    float ss = 0.f;
    #pragma unroll
    for (int i = 0; i < 3; i++){ v[i] = src[threadIdx.x + i*256]; ss += v[i]*v[i]; }
    #pragma unroll
    for (int m = 1; m < 64; m <<= 1) ss += __shfl_xor(ss, m);
    __shared__ float red[4];
    if ((threadIdx.x & 63) == 0) red[threadIdx.x >> 6] = ss;
    __syncthreads();
    float tot = red[0] + red[1] + red[2] + red[3];
    float scale = 1.0f / fmaxf(sqrtf(tot), 1e-12f);
    float* fdst = (isimg ? img_f : txt_f) + (size_t)row * DIM;
    float* odst = (isimg ? out2  : out3 ) + (size_t)row * DIM;
    unsigned short* hid = (isimg ? X2hi : X1hi) + (size_t)row * DIM2;
    unsigned short* lod = (isimg ? X2lo : X1lo) + (size_t)row * DIM2;
    #pragma unroll
    for (int i = 0; i < 3; i++){
        int c = threadIdx.x + i*256;
        float y = v[i] * scale;
        fdst[c] = y; odst[c] = y;
        unsigned short h = f2bf(y);
        hid[c] = h; lod[c] = f2bf(y - bf2f(h));
    }
}

// ---------- transpose W [1536][768] -> Wt [768][1536] (fp32) ----------
__global__ __launch_bounds__(256) void transpose_kernel(
    const float* __restrict__ Wd, const float* __restrict__ Wc,
    float* __restrict__ Td, float* __restrict__ Tc)
{
    __shared__ float t[32][33];
    const float* W = blockIdx.z ? Wc : Wd;
    float*       T = blockIdx.z ? Tc : Td;
    int x0 = blockIdx.x * 32;
    int y0 = blockIdx.y * 32;
    int tx = threadIdx.x & 31, ty = threadIdx.x >> 5;
    #pragma unroll
    for (int i = 0; i < 32; i += 8)
        t[ty + i][tx] = W[(size_t)(y0 + ty + i) * DIM + x0 + tx];
    __syncthreads();
    #pragma unroll
    for (int i = 0; i < 32; i += 8)
        T[(size_t)(x0 + ty + i) * DIM2 + y0 + tx] = t[tx][ty + i];
}

#define EPI_TOP2      0
#define EPI_BIAS_RELU 1
#define EPI_BIAS      2
#define EPI_SCALE     3

// ---------- big GEMM: C = A * B^T, both operands pre-split bf16, gload_lds staged ----------
// m97/m103 proven shape: 128x128 tile, 4 waves (2x2), per-wave 64x64, 64 KiB LDS total
// -> 2 blocks/CU. LDS rows: 128B = 8 granules of 16B, granule-XOR (row&7) swizzle via
// pre-swizzled global source. Plain 2-phase loop (stage next / compute cur / barrier).
// NTERMS==3: KS=32, row=[hi k0..31 | lo k0..31], 3 MFMA/frag-pair (split-bf16).
// NTERMS==2: KS=64, row=[hi k0..31 | hi k32..63] (pass Alo=Ahi+32 etc), plain bf16.
template<int NTERMS, int EPI>
__global__ __launch_bounds__(256, 2) void gemm_big(
    const unsigned short* __restrict__ Ahi, const unsigned short* __restrict__ Alo, int lda,
    const unsigned short* __restrict__ Bhi, const unsigned short* __restrict__ Blo, int ldb,
    int K, int Nout,
    float* __restrict__ outp, const float* __restrict__ scale_ptr, int Mtot)
{
    constexpr int BM = 128, BN = 128, NT = 256;
    constexpr int ABYTES = BM * 128, BBYTES = BN * 128, BUF = ABYTES + BBYTES; // 32 KiB
    constexpr int KS = (NTERMS == 3) ? 32 : 64;
    __shared__ __align__(16) char lds[2 * BUF];   // 64 KiB

    const int tid = threadIdx.x, lane = tid & 63, wid = tid >> 6;
    const int wm = wid >> 1, wn = wid & 1;
    const int lr = lane & 15, lg = lane >> 4;
    // chunked XCD swizzle: grid 2048 = 512 nb x 4 mb; each XCD gets a contiguous
    // l-range so the 4 mb-blocks of one nb are temporally close on one XCD (B L2 reuse).
    const int id = blockIdx.x;
    const int l  = (id & 7) * 256 + (id >> 3);
    const int nb = l >> 2, mb = l & 3;
    const int m0 = mb * BM, n0 = nb * BN;

    f32x4 acc[4][4] = {};

    auto stage = [&](int buf, int k0){
        char* base = lds + buf * BUF;
        #pragma unroll
        for (int r = 0; r < 4; r++){
            int G = r * NT + tid, row = G >> 3, slot = G & 7, s0 = slot ^ (row & 7);
            const unsigned short* s = ((s0 < 4) ? Ahi : Alo) + (size_t)(m0 + row) * lda + k0 + (s0 & 3) * 8;
            __builtin_amdgcn_global_load_lds(
                (const __attribute__((address_space(1))) void*)s,
                (__attribute__((address_space(3))) void*)(base + (r * NT + (tid & ~63)) * 16), 16, 0, 0);
        }
        #pragma unroll
        for (int r = 0; r < 4; r++){
            int G = r * NT + tid, row = G >> 3, slot = G & 7, s0 = slot ^ (row & 7);
            const unsigned short* s = ((s0 < 4) ? Bhi : Blo) + (size_t)(n0 + row) * ldb + k0 + (s0 & 3) * 8;
            __builtin_amdgcn_global_load_lds(
                (const __attribute__((address_space(1))) void*)s,
                (__attribute__((address_space(3))) void*)(base + ABYTES + (r * NT + (tid & ~63)) * 16), 16, 0, 0);
        }
    };

    auto compute = [&](int buf){
        const char* Ab = lds + buf * BUF;
        const char* Bb = Ab + ABYTES;
        bf16x8 ah[4], al[4], bh[4], bl[4];
        #pragma unroll
        for (int f = 0; f < 4; f++){
            int rowa = wm * 64 + f * 16 + lr;
            const char* rpa = Ab + rowa * 128;
            ah[f] = *(const bf16x8*)(rpa + ((lg ^ (rowa & 7)) << 4));
            al[f] = *(const bf16x8*)(rpa + (((4 + lg) ^ (rowa & 7)) << 4));
            int rowb = wn * 64 + f * 16 + lr;
            const char* rpb = Bb + rowb * 128;
            bh[f] = *(const bf16x8*)(rpb + ((lg ^ (rowb & 7)) << 4));
            bl[f] = *(const bf16x8*)(rpb + (((4 + lg) ^ (rowb & 7)) << 4));
        }
        #pragma unroll
        for (int mf = 0; mf < 4; mf++)
        #pragma unroll
        for (int nf = 0; nf < 4; nf++){
            if (NTERMS == 3){
                acc[mf][nf] = __builtin_amdgcn_mfma_f32_16x16x32_bf16(ah[mf], bh[nf], acc[mf][nf], 0, 0, 0);
                acc[mf][nf] = __builtin_amdgcn_mfma_f32_16x16x32_bf16(al[mf], bh[nf], acc[mf][nf], 0, 0, 0);
                acc[mf][nf] = __builtin_amdgcn_mfma_f32_16x16x32_bf16(ah[mf], bl[nf], acc[mf][nf], 0, 0, 0);
            } else {
                acc[mf][nf] = __builtin_amdgcn_mfma_f32_16x16x32_bf16(ah[mf], bh[nf], acc[mf][nf], 0, 0, 0);
                acc[mf][nf] = __builtin_amdgcn_mfma_f32_16x16x32_bf16(al[mf], bl[nf], acc[mf][nf], 0, 0, 0);
            }
        }
    };

    stage(0, 0);
    __syncthreads();
    const int nk = K / KS;
    int cur = 0;
    for (int kt = 0; kt < nk; kt++){
        if (kt + 1 < nk) stage(cur ^ 1, (kt + 1) * KS);
        compute(cur);
        __syncthreads();
        cur ^= 1;
    }

    if constexpr (EPI == EPI_TOP2){
        T2* t2l = (T2*)lds;   // [2][128]
        #pragma unroll
        for (int mf = 0; mf < 4; mf++){
            #pragma unroll
            for (int r = 0; r < 4; r++){
                T2 t = t2_init();
                #pragma unroll
                for (int nf = 0; nf < 4; nf++){
                    int gc = n0 + wn * 64 + nf * 16 + lr;
                    t2_add(t, acc[mf][nf][r], gc);
                }
                #pragma unroll
                for (int m = 1; m < 16; m <<= 1){
                    float ov1 = __shfl_xor(t.v1, m), ov2 = __shfl_xor(t.v2, m);
                    int   oi1 = __shfl_xor(t.i1, m), oi2 = __shfl_xor(t.i2, m);
                    t2_add(t, ov1, oi1); t2_add(t, ov2, oi2);
                }
                if (lr == 0){
                    int rowit = wm * 64 + mf * 16 + lg * 4 + r;
                    t2l[wn * 128 + rowit] = t;
                }
            }
        }
        __syncthreads();
        if (tid < 128){
            T2 t = t2l[tid];
            T2 o = t2l[128 + tid];
            t2_add(t, o.v1, o.i1); t2_add(t, o.v2, o.i2);
            f32x4 pk; pk[0] = t.v1; pk[1] = __int_as_float(t.i1); pk[2] = t.v2; pk[3] = __int_as_float(t.i2);
            ((f32x4*)outp)[(size_t)nb * Mtot + (m0 + tid)] = pk;
        }
    } else if constexpr (EPI == EPI_SCALE){
        float sc = scale_ptr[0];
        #pragma unroll
        for (int mf = 0; mf < 4; mf++)
        #pragma unroll
        for (int nf = 0; nf < 4; nf++)
        #pragma unroll
        for (int r = 0; r < 4; r++){
            int grow = m0 + wm * 64 + mf * 16 + lg * 4 + r;
            int gcol = n0 + wn * 64 + nf * 16 + lr;
            outp[(size_t)grow * Nout + gcol] = acc[mf][nf][r] * sc;
        }
    }
}

// ---------- small GEMM (MLP layers): A bf16 hi/lo, B fp32 with in-kernel convert ----------
template<int BM,int BN,int WGM,int WGN,int EPI>
__global__ __launch_bounds__(WGM*WGN*64) void gemm_small(
    const unsigned short* __restrict__ Ahi, const unsigned short* __restrict__ Alo, int lda,
    const float* __restrict__ B, int ldb, int K,
    const float* __restrict__ bias,
    unsigned short* __restrict__ dsthi, unsigned short* __restrict__ dstlo, int ldd, int dstoff)
{
    constexpr int WM = BM / WGM, WN = BN / WGN;
    constexpr int MF = WM / 16, NF = WN / 16;
    constexpr int NT = WGM * WGN * 64;
    constexpr int ABYTES = BM * 128;
    constexpr int BBYTES = BN * 128;
    constexpr int BUF = ABYTES + BBYTES;
    static_assert(BN * 4 == NT, "");
    static_assert((BM * 8) % NT == 0, "");

    __shared__ __align__(16) char lds[2 * BUF];

    const int tid  = threadIdx.x;
    const int wid  = tid >> 6, lane = tid & 63;
    const int wm   = wid / WGN, wn = wid % WGN;
    const int lr   = lane & 15, lg = lane >> 4;
    const int nb   = blockIdx.x, mb = blockIdx.y;
    const int m0   = mb * BM, n0 = nb * BN;

    f32x4 acc[MF][NF] = {};
    f32x4 breg0, breg1;

    auto stageA = [&](int buf, int k0){
        char* base = lds + buf * BUF;
        constexpr int RA = BM * 8 / NT;
        #pragma unroll
        for (int r = 0; r < RA; r++){
            int G = r * NT + tid;
            int row = G >> 3, slot = G & 7;
            int s0 = slot ^ (row & 7);
            const unsigned short* src = ((s0 < 4) ? Ahi : Alo)
                + (size_t)(m0 + row) * lda + (k0 + (s0 & 3) * 8);
            char* ldst = base + r * NT * 16 + (tid & ~63) * 16;
            __builtin_amdgcn_global_load_lds(
                (const __attribute__((address_space(1))) void*)src,
                (__attribute__((address_space(3))) void*)ldst, 16, 0, 0);
        }
    };
    auto loadB = [&](int kt){
        int k0 = kt * 32;
        int row = tid >> 2, quad = tid & 3;
        const float* bp = B + (size_t)(n0 + row) * ldb + k0 + quad * 8;
        breg0 = *(const f32x4*)bp;
        breg1 = *(const f32x4*)(bp + 4);
    };
    auto writeB = [&](int buf){
        char* base = lds + buf * BUF + ABYTES;
        int row = tid >> 2, quad = tid & 3;
        u16x8 h8, l8;
        #pragma unroll
        for (int j = 0; j < 8; j++){
            float x = (j < 4) ? breg0[j] : breg1[j - 4];
            unsigned short h = f2bf(x);
            h8[j] = h; l8[j] = f2bf(x - bf2f(h));
        }
        int sh = quad ^ (row & 7), sl = (4 + quad) ^ (row & 7);
        *(u16x8*)(base + row * 128 + sh * 16) = h8;
        *(u16x8*)(base + row * 128 + sl * 16) = l8;
    };
    auto compute = [&](int buf){
        const char* Ab = lds + buf * BUF;
        const char* Bb = Ab + ABYTES;
        bf16x8 ah[MF], al[MF], bh[NF], bl[NF];
        #pragma unroll
        for (int mf = 0; mf < MF; mf++){
            int row = wm * WM + mf * 16 + lr;
            const char* rp = Ab + row * 128;
            ah[mf] = *(const bf16x8*)(rp + ((lg ^ (row & 7)) << 4));
            al[mf] = *(const bf16x8*)(rp + (((4 + lg) ^ (row & 7)) << 4));
        }
        #pragma unroll
        for (int nf = 0; nf < NF; nf++){
            int row = wn * WN + nf * 16 + lr;
            const char* rp = Bb + row * 128;
            bh[nf] = *(const bf16x8*)(rp + ((lg ^ (row & 7)) << 4));
            bl[nf] = *(const bf16x8*)(rp + (((4 + lg) ^ (row & 7)) << 4));
        }
        #pragma unroll
        for (int mf = 0; mf < MF; mf++)
        #pragma unroll
        for (int nf = 0; nf < NF; nf++){
            acc[mf][nf] = __builtin_amdgcn_mfma_f32_16x16x32_bf16(ah[mf], bh[nf], acc[mf][nf], 0, 0, 0);
            acc[mf][nf] = __builtin_amdgcn_mfma_f32_16x16x32_bf16(al[mf], bh[nf], acc[mf][nf], 0, 0, 0);
            acc[mf][nf] = __builtin_amdgcn_mfma_f32_16x16x32_bf16(ah[mf], bl[nf], acc[mf][nf], 0, 0, 0);
        }
    };

    stageA(0, 0); loadB(0); writeB(0);
    __syncthreads();
    const int nk = K / 32;
    int cur = 0;
    for (int kt = 0; kt < nk; kt++){
        if (kt + 1 < nk){ stageA(cur ^ 1, (kt + 1) * 32); loadB(kt + 1); }
        compute(cur);
        if (kt + 1 < nk){ writeB(cur ^ 1); }
        __syncthreads();
        cur ^= 1;
    }

    #pragma unroll
    for (int mf = 0; mf < MF; mf++)
    #pragma unroll
    for (int nf = 0; nf < NF; nf++)
    #pragma unroll
    for (int r = 0; r < 4; r++){
        int grow = m0 + wm * WM + mf * 16 + lg * 4 + r;
        int gcol = n0 + wn * WN + nf * 16 + lr;
        float c = acc[mf][nf][r] + bias[gcol];
        if (EPI == EPI_BIAS_RELU) c = fmaxf(c, 0.f);
        unsigned short h = f2bf(c);
        size_t o = (size_t)grow * ldd + dstoff + gcol;
        dsthi[o] = h;
        dstlo[o] = f2bf(c - bf2f(h));
    }
}

// ---------- phase B: global top-2 merge + exact fp32 rescore -> argmax index ----------
__global__ __launch_bounds__(64) void phaseB_kernel(
    const f32x4* __restrict__ top2ws, int ntiles,
    const float* __restrict__ img_f, const float* __restrict__ qtxt,
    float* __restrict__ out_ind, int* __restrict__ ws_ind)
{
    int row = blockIdx.x;
    int lane = threadIdx.x;
    T2 t = t2_init();
    for (int j = lane; j < ntiles; j += 64){
        f32x4 e = top2ws[(size_t)j * BATCH + row];
        t2_add(t, e[0], __float_as_int(e[1]));
        t2_add(t, e[2], __float_as_int(e[3]));
    }
    #pragma unroll
    for (int m = 1; m < 64; m <<= 1){
        float ov1 = __shfl_xor(t.v1, m), ov2 = __shfl_xor(t.v2, m);
        int   oi1 = __shfl_xor(t.i1, m), oi2 = __shfl_xor(t.i2, m);
        t2_add(t, ov1, oi1); t2_add(t, ov2, oi2);
    }
    const float* a  = img_f + (size_t)row * DIM;
    const float* b1 = qtxt + (size_t)t.i1 * DIM;
    const float* b2 = qtxt + (size_t)t.i2 * DIM;
    float s1 = 0.f, s2 = 0.f;
    for (int c = lane; c < DIM; c += 64){ float av = a[c]; s1 += av * b1[c]; s2 += av * b2[c]; }
    #pragma unroll
    for (int m = 1; m < 64; m <<= 1){ s1 += __shfl_xor(s1, m); s2 += __shfl_xor(s2, m); }
    int ind = (s2 > s1 || (s2 == s1 && t.i2 < t.i1)) ? t.i2 : t.i1;
    if (lane == 0){ out_ind[row] = (float)ind; ws_ind[row] = ind; }
}

// ---------- gather t_similar rows into X1[:, 768:1536] as bf16 hi/lo ----------
__global__ __launch_bounds__(256) void gather_kernel(
    const int* __restrict__ ws_ind, const float* __restrict__ qtxt,
    unsigned short* __restrict__ X1hi, unsigned short* __restrict__ X1lo)
{
    int row = blockIdx.x;
    int ind = ws_ind[row];
    const float* src = qtxt + (size_t)ind * DIM;
    for (int c = threadIdx.x; c < DIM; c += 256){
        float x = src[c];
        unsigned short h = f2bf(x);
        X1hi[(size_t)row * DIM2 + DIM + c] = h;
        X1lo[(size_t)row * DIM2 + DIM + c] = f2bf(x - bf2f(h));
    }
}

extern "C" void kernel_launch(void* const* d_in, const int* in_sizes, int n_in,
                              void* d_out, int out_size, void* d_ws, size_t ws_size,
                              hipStream_t stream)
{
    (void)in_sizes; (void)n_in; (void)out_size; (void)ws_size;
    const float* img  = (const float*)d_in[0];
    const float* txt  = (const float*)d_in[1];
    const float* qimg = (const float*)d_in[2];
    const float* qtxt = (const float*)d_in[3];
    const float* Wd   = (const float*)d_in[4];
    const float* bd   = (const float*)d_in[5];
    const float* Wc   = (const float*)d_in[6];
    const float* bc   = (const float*)d_in[7];
    const float* ls   = (const float*)d_in[8];

    float* out0 = (float*)d_out;                    // logits [512][65536]
    float* out1 = out0 + (size_t)BATCH * NQ;        // ind_similar [512] (as f32)
    float* out2 = out1 + BATCH;                     // new_queue_img [65536][768]
    float* out3 = out2 + (size_t)NQ * DIM;          // new_queue_txt [65536][768]

    char* w = (char*)d_ws;
    auto alloc = [&](size_t bytes){ char* p = w; w += (bytes + 255) & ~(size_t)255; return p; };
    unsigned short* X1hi  = (unsigned short*)alloc((size_t)BATCH * DIM2 * 2);
    unsigned short* X1lo  = (unsigned short*)alloc((size_t)BATCH * DIM2 * 2);
    unsigned short* X2hi  = (unsigned short*)alloc((size_t)BATCH * DIM2 * 2);
    unsigned short* X2lo  = (unsigned short*)alloc((size_t)BATCH * DIM2 * 2);
    unsigned short* combhi= (unsigned short*)alloc((size_t)BATCH * DIM * 2);
    unsigned short* comblo= (unsigned short*)alloc((size_t)BATCH * DIM * 2);
    float* img_f  = (float*)alloc((size_t)BATCH * DIM * 4);
    float* txt_f  = (float*)alloc((size_t)BATCH * DIM * 4);
    float* Td     = (float*)alloc((size_t)DIM * DIM2 * 4);
    float* Tc     = (float*)alloc((size_t)DIM * DIM2 * 4);
    float* top2ws = (float*)alloc((size_t)(NQ / 128) * BATCH * 16);
    int*   ws_ind = (int*)alloc(BATCH * 4);
    unsigned short* Bt_hi = (unsigned short*)alloc((size_t)NQ * DIM * 2);
    unsigned short* Bt_lo = (unsigned short*)alloc((size_t)NQ * DIM * 2);
    unsigned short* Bi_hi = (unsigned short*)alloc((size_t)NQ * DIM * 2);

    // 1) convert queues to bf16 hi/lo + full fp32 passthrough into out2/out3
    convert_kernel<<<dim3(2048, 2), dim3(256), 0, stream>>>(
        qtxt, qimg, Bt_hi, Bt_lo, Bi_hi, out3, out2);

    // 2) normalize features (overwrites out2/out3 rows 0..511), split to hi/lo
    prep_kernel<<<dim3(2 * BATCH), dim3(256), 0, stream>>>(
        img, txt, img_f, txt_f, X2hi, X2lo, X1hi, X1lo, out2, out3);

    // 3) transpose weights to [768][1536] fp32
    transpose_kernel<<<dim3(DIM / 32, DIM2 / 32, 2), dim3(256), 0, stream>>>(Wd, Wc, Td, Tc);

    // 4) retrieval GEMM (split-bf16, 3 terms) + per-tile top2  [grid 2048 = 512 nb x 4 mb]
    gemm_big<3, EPI_TOP2><<<dim3(2048), dim3(256), 0, stream>>>(
        X2hi, X2lo, DIM2, Bt_hi, Bt_lo, DIM, DIM, NQ, top2ws, nullptr, BATCH);

    // 5) global top-2 + exact rescore -> ind_similar
    phaseB_kernel<<<dim3(BATCH), dim3(64), 0, stream>>>(
        (const f32x4*)top2ws, NQ / 128, img_f, qtxt, out1, ws_ind);

    // 6) gather t_similar into X1[:, 768:]
    gather_kernel<<<dim3(BATCH), dim3(256), 0, stream>>>(ws_ind, qtxt, X1hi, X1lo);

    // 7) diff = relu(X1 @ W_diff + b_diff) -> X2[:, 768:] (split)
    gemm_small<64,64,2,2,EPI_BIAS_RELU><<<dim3(DIM / 64, BATCH / 64), dim3(256), 0, stream>>>(
        X1hi, X1lo, DIM2, Td, DIM2, DIM2, bd, X2hi, X2lo, DIM2, DIM);

    // 8) combined = X2 @ W_comb + b_comb -> comb hi/lo
    gemm_small<64,64,2,2,EPI_BIAS><<<dim3(DIM / 64, BATCH / 64), dim3(256), 0, stream>>>(
        X2hi, X2lo, DIM2, Tc, DIM2, DIM2, bc, combhi, comblo, DIM, 0);

    // 9) logits = scale * combined @ queue_img^T   (K64 hi-only mode: lo = hi + 32)
    gemm_big<2, EPI_SCALE><<<dim3(2048), dim3(256), 0, stream>>>(
        combhi, combhi + 32, DIM, Bi_hi, Bi_hi + 32, DIM, DIM, NQ, out0, ls, BATCH);
}

// Round 7
// 568.046 us; speedup vs baseline: 1.2086x; 1.1004x over previous
//
#include <hip/hip_runtime.h>
#include <stdint.h>
#include <stddef.h>

#define BATCH 512
#define NQ    65536
#define DIM   768
#define DIM2  1536

typedef __attribute__((ext_vector_type(4))) float f32x4;
typedef __attribute__((ext_vector_type(4))) unsigned short u16x4;
typedef __attribute__((ext_vector_type(8))) unsigned short u16x8;
typedef __attribute__((ext_vector_type(8))) __bf16 bf16x8;

// ---------- fp32 <-> bf16 (round-to-nearest-even) ----------
static __device__ __forceinline__ unsigned short f2bf(float x){
    unsigned int u = __float_as_uint(x);
    unsigned int r = ((u >> 16) & 1u) + 0x7fffu;
    return (unsigned short)((u + r) >> 16);
}
static __device__ __forceinline__ float bf2f(unsigned short h){
    return __uint_as_float(((unsigned int)h) << 16);
}

// ---------- top-2 tracking ----------
struct T2 { float v1, v2; int i1, i2; };
static __device__ __forceinline__ void t2_add(T2& t, float v, int i){
    if (v > t.v1 || (v == t.v1 && i < t.i1)) { t.v2 = t.v1; t.i2 = t.i1; t.v1 = v; t.i1 = i; }
    else if (v > t.v2 || (v == t.v2 && i < t.i2)) { t.v2 = v; t.i2 = i; }
}
static __device__ __forceinline__ T2 t2_init(){ T2 t; t.v1 = -3.4e38f; t.v2 = -3.4e38f; t.i1 = 0x7fffffff; t.i2 = 0x7fffffff; return t; }

// ---------- convert: queues fp32 -> bf16 hi/lo, fused new_queue passthrough ----------
__global__ __launch_bounds__(256) void convert_kernel(
    const float* __restrict__ qtxt, const float* __restrict__ qimg,
    unsigned short* __restrict__ bthi, unsigned short* __restrict__ btlo,
    unsigned short* __restrict__ bihi,
    float* __restrict__ out3, float* __restrict__ out2)
{
    const bool isT = (blockIdx.y == 0);
    const float* __restrict__ src = isT ? qtxt : qimg;
    float* __restrict__ dst = isT ? out3 : out2;
    unsigned short* __restrict__ hi = isT ? bthi : bihi;
    unsigned short* __restrict__ lo = btlo;
    const size_t n4 = (size_t)NQ * DIM / 4;
    for (size_t i = (size_t)blockIdx.x * 256 + threadIdx.x; i < n4; i += (size_t)gridDim.x * 256) {
        f32x4 v = ((const f32x4*)src)[i];
        ((f32x4*)dst)[i] = v;
        u16x4 h, l;
        #pragma unroll
        for (int j = 0; j < 4; j++){
            unsigned short hh = f2bf(v[j]);
            h[j] = hh; l[j] = f2bf(v[j] - bf2f(hh));
        }
        *(u16x4*)(hi + 4*i) = h;
        if (isT) *(u16x4*)(lo + 4*i) = l;
    }
}

// ---------- prep: L2-normalize features, split to bf16 hi/lo, seed queue rows ----------
__global__ __launch_bounds__(256) void prep_kernel(
    const float* __restrict__ img, const float* __restrict__ txt,
    float* __restrict__ img_f, float* __restrict__ txt_f,
    unsigned short* __restrict__ X2hi, unsigned short* __restrict__ X2lo,
    unsigned short* __restrict__ X1hi, unsigned short* __restrict__ X1lo,
    float* __restrict__ out2, float* __restrict__ out3)
{
    int b = blockIdx.x;
    bool isimg = (b < BATCH);
    int row = isimg ? b : b - BATCH;
    const float* src = (isimg ? img : txt) + (size_t)row * DIM;
    float v[3];
    float ss = 0.f;
    #pragma unroll
    for (int i = 0; i < 3; i++){ v[i] = src[threadIdx.x + i*256]; ss += v[i]*v[i]; }
    #pragma unroll
    for (int m = 1; m < 64; m <<= 1) ss += __shfl_xor(ss, m);
    __shared__ float red[4];
    if ((threadIdx.x & 63) == 0) red[threadIdx.x >> 6] = ss;
    __syncthreads();
    float tot = red[0] + red[1] + red[2] + red[3];
    float scale = 1.0f / fmaxf(sqrtf(tot), 1e-12f);
    float* fdst = (isimg ? img_f : txt_f) + (size_t)row * DIM;
    float* odst = (isimg ? out2  : out3 ) + (size_t)row * DIM;
    unsigned short* hid = (isimg ? X2hi : X1hi) + (size_t)row * DIM2;
    unsigned short* lod = (isimg ? X2lo : X1lo) + (size_t)row * DIM2;
    #pragma unroll
    for (int i = 0; i < 3; i++){
        int c = threadIdx.x + i*256;
        float y = v[i] * scale;
        fdst[c] = y; odst[c] = y;
        unsigned short h = f2bf(y);
        hid[c] = h; lod[c] = f2bf(y - bf2f(h));
    }
}

// ---------- transpose W [1536][768] -> Wt [768][1536] (fp32) ----------
__global__ __launch_bounds__(256) void transpose_kernel(
    const float* __restrict__ Wd, const float* __restrict__ Wc,
    float* __restrict__ Td, float* __restrict__ Tc)
{
    __shared__ float t[32][33];
    const float* W = blockIdx.z ? Wc : Wd;
    float*       T = blockIdx.z ? Tc : Td;
    int x0 = blockIdx.x * 32;
    int y0 = blockIdx.y * 32;
    int tx = threadIdx.x & 31, ty = threadIdx.x >> 5;
    #pragma unroll
    for (int i = 0; i < 32; i += 8)
        t[ty + i][tx] = W[(size_t)(y0 + ty + i) * DIM + x0 + tx];
    __syncthreads();
    #pragma unroll
    for (int i = 0; i < 32; i += 8)
        T[(size_t)(x0 + ty + i) * DIM2 + y0 + tx] = t[tx][ty + i];
}

#define EPI_TOP2      0
#define EPI_BIAS_RELU 1
#define EPI_BIAS      2
#define EPI_SCALE     3

// ---------- big GEMM: m201-faithful 8-phase schedule, pre-split bf16 operands ----------
// BM=BN=256, 8 waves (2M x 4N), per-wave 128x64 output, acc[8][4].
// LDS: per K-step buffer = 4 half-tiles (A0,A1,B0,B1) x 16KB; double-buffered = 128 KiB.
// Row = 128B = 8 granules of 16B, granule-XOR (row&7) swizzle via pre-swizzled source.
// NTERMS==3: KS=32, row=[hi k0..31 | lo k0..31], 3 MFMA/frag-pair (split-bf16).
// NTERMS==2: KS=64, row=[hi k0..31 | hi k32..63] (Alo=Ahi+32), 2 MFMA/frag-pair.
// Per K-step kt, 4 phases q: stage {q<2: A_q(kt+1), q>=2: B_(q-2)(kt+2)} || ds_read
// (q==0: all 8 B-frags; every q: 4 A-frags of mf pair 2q,2q+1) -> s_barrier ->
// lgkmcnt(0) -> sched_barrier -> setprio(1) -> 24/16 MFMA -> setprio(0) ->
// [q==3: vmcnt(4), tail: vmcnt(0)] -> s_barrier. Never drains vmcnt mid-loop (T4).
// Ledger: vmcnt(4) at (kt,3) leaves exactly B(kt+2)'s 4 loads outstanding => everything
// K-step kt+1 reads is complete. B(kt) slots are reg-consumed at phase 0 (lgkm0+barrier)
// before B(kt+2) stages land; A(kt+1) slot's tenant A(kt-1) retired at (kt-1,3).
template<int NTERMS, int EPI>
__global__ __launch_bounds__(512, 2) void gemm_big(
    const unsigned short* __restrict__ Ahi, const unsigned short* __restrict__ Alo, int lda,
    const unsigned short* __restrict__ Bhi, const unsigned short* __restrict__ Blo, int ldb,
    int K, int Nout,
    float* __restrict__ outp, const float* __restrict__ scale_ptr, int Mtot)
{
    constexpr int NT = 512;
    constexpr int KS = (NTERMS == 3) ? 32 : 64;
    constexpr int HT = 16384;           // half-tile bytes: 128 rows x 128B
    constexpr int BUF = 4 * HT;         // 64 KiB per K-step
    __shared__ __align__(16) char lds[2 * BUF];   // 128 KiB

    const int tid = threadIdx.x, lane = tid & 63, wid = tid >> 6;
    const int wm = wid >> 2, wn = wid & 3;
    const int lr = lane & 15, lg = lane >> 4;
    // chunked XCD swizzle: 512 blocks -> 64/XCD; (nb, mb) pairs adjacent on one XCD.
    const int id = blockIdx.x;
    const int l  = (id & 7) * 64 + (id >> 3);
    const int nb = l >> 1, mb = l & 1;
    const int m0 = mb * 256, n0 = nb * 256;

    f32x4 acc[8][4] = {};

    // half-tile T: kstep = T>>2, kind = T&3 (0=A0,1=A1,2=B0,3=B1)
    auto stageHT = [&](int T){
        int kind = T & 3, ks = T >> 2;
        char* base = lds + (ks & 1) * BUF + kind * HT;
        const unsigned short* hi = (kind < 2) ? Ahi : Bhi;
        const unsigned short* lo = (kind < 2) ? Alo : Blo;
        int ld = (kind < 2) ? lda : ldb;
        int r0 = ((kind < 2) ? m0 : n0) + (kind & 1) * 128;
        int k0 = ks * KS;
        #pragma unroll
        for (int r = 0; r < 2; r++){
            int G = r * NT + tid, row = G >> 3, slot = G & 7, s0 = slot ^ (row & 7);
            const unsigned short* s = ((s0 < 4) ? hi : lo) + (size_t)(r0 + row) * ld + k0 + (s0 & 3) * 8;
            __builtin_amdgcn_global_load_lds(
                (const __attribute__((address_space(1))) void*)s,
                (__attribute__((address_space(3))) void*)(base + (r * NT + (tid & ~63)) * 16), 16, 0, 0);
        }
    };

    const int xh = (lg ^ (lr & 7)) << 4;        // hi-granule byte offset (frag rows: &7 == lr&7)
    const int xl = ((4 + lg) ^ (lr & 7)) << 4;  // lo-granule byte offset

    // prologue: A0,A1,B0,B1 of kstep 0 + B0,B1 of kstep 1; wait first 4 tiles
    const int nk = K / KS;
    stageHT(0); stageHT(1); stageHT(2); stageHT(3);
    if (nk > 1){
        stageHT(6); stageHT(7);
        asm volatile("s_waitcnt vmcnt(4)" ::: "memory");
    } else {
        asm volatile("s_waitcnt vmcnt(0)" ::: "memory");
    }
    __syncthreads();

    for (int kt = 0; kt < nk; kt++){
        const char* Ab = lds + (kt & 1) * BUF;
        const char* Bb = Ab + 2 * HT;
        bf16x8 bh[4], bl[4];
        #pragma unroll
        for (int q = 0; q < 4; q++){
            if (q < 2){ if (kt + 1 < nk) stageHT(4 * (kt + 1) + q); }
            else      { if (kt + 2 < nk) stageHT(4 * (kt + 2) + q); }
            if (q == 0){
                #pragma unroll
                for (int nf = 0; nf < 4; nf++){
                    const char* rp = Bb + (wn * 64 + nf * 16 + lr) * 128;
                    bh[nf] = *(const bf16x8*)(rp + xh);
                    bl[nf] = *(const bf16x8*)(rp + xl);
                }
            }
            const char* rp0 = Ab + (wm * 128 + q * 32 + lr) * 128;
            const char* rp1 = rp0 + 16 * 128;
            bf16x8 a0h = *(const bf16x8*)(rp0 + xh);
            bf16x8 a0l = *(const bf16x8*)(rp0 + xl);
            bf16x8 a1h = *(const bf16x8*)(rp1 + xh);
            bf16x8 a1l = *(const bf16x8*)(rp1 + xl);
            asm volatile("s_barrier" ::: "memory");
            asm volatile("s_waitcnt lgkmcnt(0)" ::: "memory");
            __builtin_amdgcn_sched_barrier(0);
            __builtin_amdgcn_s_setprio(1);
            #pragma unroll
            for (int nf = 0; nf < 4; nf++){
                if (NTERMS == 3){
                    acc[2*q  ][nf] = __builtin_amdgcn_mfma_f32_16x16x32_bf16(a0h, bh[nf], acc[2*q  ][nf], 0, 0, 0);
                    acc[2*q  ][nf] = __builtin_amdgcn_mfma_f32_16x16x32_bf16(a0l, bh[nf], acc[2*q  ][nf], 0, 0, 0);
                    acc[2*q  ][nf] = __builtin_amdgcn_mfma_f32_16x16x32_bf16(a0h, bl[nf], acc[2*q  ][nf], 0, 0, 0);
                    acc[2*q+1][nf] = __builtin_amdgcn_mfma_f32_16x16x32_bf16(a1h, bh[nf], acc[2*q+1][nf], 0, 0, 0);
                    acc[2*q+1][nf] = __builtin_amdgcn_mfma_f32_16x16x32_bf16(a1l, bh[nf], acc[2*q+1][nf], 0, 0, 0);
                    acc[2*q+1][nf] = __builtin_amdgcn_mfma_f32_16x16x32_bf16(a1h, bl[nf], acc[2*q+1][nf], 0, 0, 0);
                } else {
                    acc[2*q  ][nf] = __builtin_amdgcn_mfma_f32_16x16x32_bf16(a0h, bh[nf], acc[2*q  ][nf], 0, 0, 0);
                    acc[2*q  ][nf] = __builtin_amdgcn_mfma_f32_16x16x32_bf16(a0l, bl[nf], acc[2*q  ][nf], 0, 0, 0);
                    acc[2*q+1][nf] = __builtin_amdgcn_mfma_f32_16x16x32_bf16(a1h, bh[nf], acc[2*q+1][nf], 0, 0, 0);
                    acc[2*q+1][nf] = __builtin_amdgcn_mfma_f32_16x16x32_bf16(a1l, bl[nf], acc[2*q+1][nf], 0, 0, 0);
                }
            }
            __builtin_amdgcn_s_setprio(0);
            if (q == 3){
                if (kt < nk - 2)       asm volatile("s_waitcnt vmcnt(4)" ::: "memory");
                else if (kt == nk - 2) asm volatile("s_waitcnt vmcnt(0)" ::: "memory");
            }
            asm volatile("s_barrier" ::: "memory");
        }
    }

    if constexpr (EPI == EPI_TOP2){
        T2* t2l = (T2*)lds;   // [4][256]
        #pragma unroll
        for (int mf = 0; mf < 8; mf++){
            #pragma unroll
            for (int r = 0; r < 4; r++){
                T2 t = t2_init();
                #pragma unroll
                for (int nf = 0; nf < 4; nf++){
                    int gc = n0 + wn * 64 + nf * 16 + lr;
                    t2_add(t, acc[mf][nf][r], gc);
                }
                #pragma unroll
                for (int m = 1; m < 16; m <<= 1){
                    float ov1 = __shfl_xor(t.v1, m), ov2 = __shfl_xor(t.v2, m);
                    int   oi1 = __shfl_xor(t.i1, m), oi2 = __shfl_xor(t.i2, m);
                    t2_add(t, ov1, oi1); t2_add(t, ov2, oi2);
                }
                if (lr == 0){
                    int rowit = wm * 128 + mf * 16 + lg * 4 + r;
                    t2l[wn * 256 + rowit] = t;
                }
            }
        }
        __syncthreads();
        if (tid < 256){
            T2 t = t2l[tid];
            #pragma unroll
            for (int w = 1; w < 4; w++){
                T2 o = t2l[w * 256 + tid];
                t2_add(t, o.v1, o.i1); t2_add(t, o.v2, o.i2);
            }
            f32x4 pk; pk[0] = t.v1; pk[1] = __int_as_float(t.i1); pk[2] = t.v2; pk[3] = __int_as_float(t.i2);
            ((f32x4*)outp)[(size_t)nb * Mtot + (m0 + tid)] = pk;
        }
    } else if constexpr (EPI == EPI_SCALE){
        float sc = scale_ptr[0];
        #pragma unroll
        for (int mf = 0; mf < 8; mf++)
        #pragma unroll
        for (int nf = 0; nf < 4; nf++)
        #pragma unroll
        for (int r = 0; r < 4; r++){
            int grow = m0 + wm * 128 + mf * 16 + lg * 4 + r;
            int gcol = n0 + wn * 64 + nf * 16 + lr;
            outp[(size_t)grow * Nout + gcol] = acc[mf][nf][r] * sc;
        }
    }
}

// ---------- small GEMM (MLP layers): A bf16 hi/lo, B fp32 with in-kernel convert ----------
template<int BM,int BN,int WGM,int WGN,int EPI>
__global__ __launch_bounds__(WGM*WGN*64) void gemm_small(
    const unsigned short* __restrict__ Ahi, const unsigned short* __restrict__ Alo, int lda,
    const float* __restrict__ B, int ldb, int K,
    const float* __restrict__ bias,
    unsigned short* __restrict__ dsthi, unsigned short* __restrict__ dstlo, int ldd, int dstoff)
{
    constexpr int WM = BM / WGM, WN = BN / WGN;
    constexpr int MF = WM / 16, NF = WN / 16;
    constexpr int NT = WGM * WGN * 64;
    constexpr int ABYTES = BM * 128;
    constexpr int BBYTES = BN * 128;
    constexpr int BUF = ABYTES + BBYTES;
    static_assert(BN * 4 == NT, "");
    static_assert((BM * 8) % NT == 0, "");

    __shared__ __align__(16) char lds[2 * BUF];

    const int tid  = threadIdx.x;
    const int wid  = tid >> 6, lane = tid & 63;
    const int wm   = wid / WGN, wn = wid % WGN;
    const int lr   = lane & 15, lg = lane >> 4;
    const int nb   = blockIdx.x, mb = blockIdx.y;
    const int m0   = mb * BM, n0 = nb * BN;

    f32x4 acc[MF][NF] = {};
    f32x4 breg0, breg1;

    auto stageA = [&](int buf, int k0){
        char* base = lds + buf * BUF;
        constexpr int RA = BM * 8 / NT;
        #pragma unroll
        for (int r = 0; r < RA; r++){
            int G = r * NT + tid;
            int row = G >> 3, slot = G & 7;
            int s0 = slot ^ (row & 7);
            const unsigned short* src = ((s0 < 4) ? Ahi : Alo)
                + (size_t)(m0 + row) * lda + (k0 + (s0 & 3) * 8);
            char* ldst = base + r * NT * 16 + (tid & ~63) * 16;
            __builtin_amdgcn_global_load_lds(
                (const __attribute__((address_space(1))) void*)src,
                (__attribute__((address_space(3))) void*)ldst, 16, 0, 0);
        }
    };
    auto loadB = [&](int kt){
        int k0 = kt * 32;
        int row = tid >> 2, quad = tid & 3;
        const float* bp = B + (size_t)(n0 + row) * ldb + k0 + quad * 8;
        breg0 = *(const f32x4*)bp;
        breg1 = *(const f32x4*)(bp + 4);
    };
    auto writeB = [&](int buf){
        char* base = lds + buf * BUF + ABYTES;
        int row = tid >> 2, quad = tid & 3;
        u16x8 h8, l8;
        #pragma unroll
        for (int j = 0; j < 8; j++){
            float x = (j < 4) ? breg0[j] : breg1[j - 4];
            unsigned short h = f2bf(x);
            h8[j] = h; l8[j] = f2bf(x - bf2f(h));
        }
        int sh = quad ^ (row & 7), sl = (4 + quad) ^ (row & 7);
        *(u16x8*)(base + row * 128 + sh * 16) = h8;
        *(u16x8*)(base + row * 128 + sl * 16) = l8;
    };
    auto compute = [&](int buf){
        const char* Ab = lds + buf * BUF;
        const char* Bb = Ab + ABYTES;
        bf16x8 ah[MF], al[MF], bh[NF], bl[NF];
        #pragma unroll
        for (int mf = 0; mf < MF; mf++){
            int row = wm * WM + mf * 16 + lr;
            const char* rp = Ab + row * 128;
            ah[mf] = *(const bf16x8*)(rp + ((lg ^ (row & 7)) << 4));
            al[mf] = *(const bf16x8*)(rp + (((4 + lg) ^ (row & 7)) << 4));
        }
        #pragma unroll
        for (int nf = 0; nf < NF; nf++){
            int row = wn * WN + nf * 16 + lr;
            const char* rp = Bb + row * 128;
            bh[nf] = *(const bf16x8*)(rp + ((lg ^ (row & 7)) << 4));
            bl[nf] = *(const bf16x8*)(rp + (((4 + lg) ^ (row & 7)) << 4));
        }
        #pragma unroll
        for (int mf = 0; mf < MF; mf++)
        #pragma unroll
        for (int nf = 0; nf < NF; nf++){
            acc[mf][nf] = __builtin_amdgcn_mfma_f32_16x16x32_bf16(ah[mf], bh[nf], acc[mf][nf], 0, 0, 0);
            acc[mf][nf] = __builtin_amdgcn_mfma_f32_16x16x32_bf16(al[mf], bh[nf], acc[mf][nf], 0, 0, 0);
            acc[mf][nf] = __builtin_amdgcn_mfma_f32_16x16x32_bf16(ah[mf], bl[nf], acc[mf][nf], 0, 0, 0);
        }
    };

    stageA(0, 0); loadB(0); writeB(0);
    __syncthreads();
    const int nk = K / 32;
    int cur = 0;
    for (int kt = 0; kt < nk; kt++){
        if (kt + 1 < nk){ stageA(cur ^ 1, (kt + 1) * 32); loadB(kt + 1); }
        compute(cur);
        if (kt + 1 < nk){ writeB(cur ^ 1); }
        __syncthreads();
        cur ^= 1;
    }

    #pragma unroll
    for (int mf = 0; mf < MF; mf++)
    #pragma unroll
    for (int nf = 0; nf < NF; nf++)
    #pragma unroll
    for (int r = 0; r < 4; r++){
        int grow = m0 + wm * WM + mf * 16 + lg * 4 + r;
        int gcol = n0 + wn * WN + nf * 16 + lr;
        float c = acc[mf][nf][r] + bias[gcol];
        if (EPI == EPI_BIAS_RELU) c = fmaxf(c, 0.f);
        unsigned short h = f2bf(c);
        size_t o = (size_t)grow * ldd + dstoff + gcol;
        dsthi[o] = h;
        dstlo[o] = f2bf(c - bf2f(h));
    }
}

// ---------- phase B: global top-2 merge + exact fp32 rescore -> argmax index ----------
__global__ __launch_bounds__(64) void phaseB_kernel(
    const f32x4* __restrict__ top2ws, int ntiles,
    const float* __restrict__ img_f, const float* __restrict__ qtxt,
    float* __restrict__ out_ind, int* __restrict__ ws_ind)
{
    int row = blockIdx.x;
    int lane = threadIdx.x;
    T2 t = t2_init();
    for (int j = lane; j < ntiles; j += 64){
        f32x4 e = top2ws[(size_t)j * BATCH + row];
        t2_add(t, e[0], __float_as_int(e[1]));
        t2_add(t, e[2], __float_as_int(e[3]));
    }
    #pragma unroll
    for (int m = 1; m < 64; m <<= 1){
        float ov1 = __shfl_xor(t.v1, m), ov2 = __shfl_xor(t.v2, m);
        int   oi1 = __shfl_xor(t.i1, m), oi2 = __shfl_xor(t.i2, m);
        t2_add(t, ov1, oi1); t2_add(t, ov2, oi2);
    }
    const float* a  = img_f + (size_t)row * DIM;
    const float* b1 = qtxt + (size_t)t.i1 * DIM;
    const float* b2 = qtxt + (size_t)t.i2 * DIM;
    float s1 = 0.f, s2 = 0.f;
    for (int c = lane; c < DIM; c += 64){ float av = a[c]; s1 += av * b1[c]; s2 += av * b2[c]; }
    #pragma unroll
    for (int m = 1; m < 64; m <<= 1){ s1 += __shfl_xor(s1, m); s2 += __shfl_xor(s2, m); }
    int ind = (s2 > s1 || (s2 == s1 && t.i2 < t.i1)) ? t.i2 : t.i1;
    if (lane == 0){ out_ind[row] = (float)ind; ws_ind[row] = ind; }
}

// ---------- gather t_similar rows into X1[:, 768:1536] as bf16 hi/lo ----------
__global__ __launch_bounds__(256) void gather_kernel(
    const int* __restrict__ ws_ind, const float* __restrict__ qtxt,
    unsigned short* __restrict__ X1hi, unsigned short* __restrict__ X1lo)
{
    int row = blockIdx.x;
    int ind = ws_ind[row];
    const float* src = qtxt + (size_t)ind * DIM;
    for (int c = threadIdx.x; c < DIM; c += 256){
        float x = src[c];
        unsigned short h = f2bf(x);
        X1hi[(size_t)row * DIM2 + DIM + c] = h;
        X1lo[(size_t)row * DIM2 + DIM + c] = f2bf(x - bf2f(h));
    }
}

extern "C" void kernel_launch(void* const* d_in, const int* in_sizes, int n_in,
                              void* d_out, int out_size, void* d_ws, size_t ws_size,
                              hipStream_t stream)
{
    (void)in_sizes; (void)n_in; (void)out_size; (void)ws_size;
    const float* img  = (const float*)d_in[0];
    const float* txt  = (const float*)d_in[1];
    const float* qimg = (const float*)d_in[2];
    const float* qtxt = (const float*)d_in[3];
    const float* Wd   = (const float*)d_in[4];
    const float* bd   = (const float*)d_in[5];
    const float* Wc   = (const float*)d_in[6];
    const float* bc   = (const float*)d_in[7];
    const float* ls   = (const float*)d_in[8];

    float* out0 = (float*)d_out;                    // logits [512][65536]
    float* out1 = out0 + (size_t)BATCH * NQ;        // ind_similar [512] (as f32)
    float* out2 = out1 + BATCH;                     // new_queue_img [65536][768]
    float* out3 = out2 + (size_t)NQ * DIM;          // new_queue_txt [65536][768]

    char* w = (char*)d_ws;
    auto alloc = [&](size_t bytes){ char* p = w; w += (bytes + 255) & ~(size_t)255; return p; };
    unsigned short* X1hi  = (unsigned short*)alloc((size_t)BATCH * DIM2 * 2);
    unsigned short* X1lo  = (unsigned short*)alloc((size_t)BATCH * DIM2 * 2);
    unsigned short* X2hi  = (unsigned short*)alloc((size_t)BATCH * DIM2 * 2);
    unsigned short* X2lo  = (unsigned short*)alloc((size_t)BATCH * DIM2 * 2);
    unsigned short* combhi= (unsigned short*)alloc((size_t)BATCH * DIM * 2);
    unsigned short* comblo= (unsigned short*)alloc((size_t)BATCH * DIM * 2);
    float* img_f  = (float*)alloc((size_t)BATCH * DIM * 4);
    float* txt_f  = (float*)alloc((size_t)BATCH * DIM * 4);
    float* Td     = (float*)alloc((size_t)DIM * DIM2 * 4);
    float* Tc     = (float*)alloc((size_t)DIM * DIM2 * 4);
    float* top2ws = (float*)alloc((size_t)(NQ / 256) * BATCH * 16);
    int*   ws_ind = (int*)alloc(BATCH * 4);
    unsigned short* Bt_hi = (unsigned short*)alloc((size_t)NQ * DIM * 2);
    unsigned short* Bt_lo = (unsigned short*)alloc((size_t)NQ * DIM * 2);
    unsigned short* Bi_hi = (unsigned short*)alloc((size_t)NQ * DIM * 2);

    // 1) convert queues to bf16 hi/lo + full fp32 passthrough into out2/out3
    convert_kernel<<<dim3(2048, 2), dim3(256), 0, stream>>>(
        qtxt, qimg, Bt_hi, Bt_lo, Bi_hi, out3, out2);

    // 2) normalize features (overwrites out2/out3 rows 0..511), split to hi/lo
    prep_kernel<<<dim3(2 * BATCH), dim3(256), 0, stream>>>(
        img, txt, img_f, txt_f, X2hi, X2lo, X1hi, X1lo, out2, out3);

    // 3) transpose weights to [768][1536] fp32
    transpose_kernel<<<dim3(DIM / 32, DIM2 / 32, 2), dim3(256), 0, stream>>>(Wd, Wc, Td, Tc);

    // 4) retrieval GEMM (split-bf16, 3 terms, 8-phase) + per-tile top2  [512 blocks]
    gemm_big<3, EPI_TOP2><<<dim3(512), dim3(512), 0, stream>>>(
        X2hi, X2lo, DIM2, Bt_hi, Bt_lo, DIM, DIM, NQ, top2ws, nullptr, BATCH);

    // 5) global top-2 + exact rescore -> ind_similar
    phaseB_kernel<<<dim3(BATCH), dim3(64), 0, stream>>>(
        (const f32x4*)top2ws, NQ / 256, img_f, qtxt, out1, ws_ind);

    // 6) gather t_similar into X1[:, 768:]
    gather_kernel<<<dim3(BATCH), dim3(256), 0, stream>>>(ws_ind, qtxt, X1hi, X1lo);

    // 7) diff = relu(X1 @ W_diff + b_diff) -> X2[:, 768:] (split)
    gemm_small<64,64,2,2,EPI_BIAS_RELU><<<dim3(DIM / 64, BATCH / 64), dim3(256), 0, stream>>>(
        X1hi, X1lo, DIM2, Td, DIM2, DIM2, bd, X2hi, X2lo, DIM2, DIM);

    // 8) combined = X2 @ W_comb + b_comb -> comb hi/lo
    gemm_small<64,64,2,2,EPI_BIAS><<<dim3(DIM / 64, BATCH / 64), dim3(256), 0, stream>>>(
        X2hi, X2lo, DIM2, Tc, DIM2, DIM2, bc, combhi, comblo, DIM, 0);

    // 9) logits = scale * combined @ queue_img^T (K64 hi-only, 8-phase)  [512 blocks]
    gemm_big<2, EPI_SCALE><<<dim3(512), dim3(512), 0, stream>>>(
        combhi, combhi + 32, DIM, Bi_hi, Bi_hi + 32, DIM, DIM, NQ, out0, ls, BATCH);
}

// Round 8
// 477.074 us; speedup vs baseline: 1.4390x; 1.1907x over previous
//
#include <hip/hip_runtime.h>
#include <stdint.h>
#include <stddef.h>

#define BATCH 512
#define NQ    65536
#define DIM   768
#define DIM2  1536

typedef __attribute__((ext_vector_type(4))) float f32x4;
typedef __attribute__((ext_vector_type(4))) unsigned short u16x4;
typedef __attribute__((ext_vector_type(8))) unsigned short u16x8;
typedef __attribute__((ext_vector_type(8))) __bf16 bf16x8;

// ---------- fp32 <-> bf16 (round-to-nearest-even) ----------
static __device__ __forceinline__ unsigned short f2bf(float x){
    unsigned int u = __float_as_uint(x);
    unsigned int r = ((u >> 16) & 1u) + 0x7fffu;
    return (unsigned short)((u + r) >> 16);
}
static __device__ __forceinline__ float bf2f(unsigned short h){
    return __uint_as_float(((unsigned int)h) << 16);
}

// ---------- top-2 tracking ----------
struct T2 { float v1, v2; int i1, i2; };
static __device__ __forceinline__ void t2_add(T2& t, float v, int i){
    if (v > t.v1 || (v == t.v1 && i < t.i1)) { t.v2 = t.v1; t.i2 = t.i1; t.v1 = v; t.i1 = i; }
    else if (v > t.v2 || (v == t.v2 && i < t.i2)) { t.v2 = v; t.i2 = i; }
}
static __device__ __forceinline__ T2 t2_init(){ T2 t; t.v1 = -3.4e38f; t.v2 = -3.4e38f; t.i1 = 0x7fffffff; t.i2 = 0x7fffffff; return t; }

// ---------- convert: queues fp32 -> bf16 (hi only), fused new_queue passthrough ----------
// y==0: qtxt -> Bt_hi, out3(copy).  y==1: qimg -> Bi_hi, out2(copy).
// prep_kernel runs AFTER this and overwrites out2/out3 rows 0..511 with normalized feats.
__global__ __launch_bounds__(256) void convert_kernel(
    const float* __restrict__ qtxt, const float* __restrict__ qimg,
    unsigned short* __restrict__ bthi, unsigned short* __restrict__ bihi,
    float* __restrict__ out3, float* __restrict__ out2)
{
    const bool isT = (blockIdx.y == 0);
    const float* __restrict__ src = isT ? qtxt : qimg;
    float* __restrict__ dst = isT ? out3 : out2;
    unsigned short* __restrict__ hi = isT ? bthi : bihi;
    const size_t n4 = (size_t)NQ * DIM / 4;
    for (size_t i = (size_t)blockIdx.x * 256 + threadIdx.x; i < n4; i += (size_t)gridDim.x * 256) {
        f32x4 v = ((const f32x4*)src)[i];
        ((f32x4*)dst)[i] = v;
        u16x4 h;
        #pragma unroll
        for (int j = 0; j < 4; j++) h[j] = f2bf(v[j]);
        *(u16x4*)(hi + 4*i) = h;
    }
}

// ---------- prep: L2-normalize features, split to bf16 hi/lo, seed queue rows ----------
__global__ __launch_bounds__(256) void prep_kernel(
    const float* __restrict__ img, const float* __restrict__ txt,
    float* __restrict__ img_f, float* __restrict__ txt_f,
    unsigned short* __restrict__ X2hi, unsigned short* __restrict__ X2lo,
    unsigned short* __restrict__ X1hi, unsigned short* __restrict__ X1lo,
    float* __restrict__ out2, float* __restrict__ out3)
{
    int b = blockIdx.x;
    bool isimg = (b < BATCH);
    int row = isimg ? b : b - BATCH;
    const float* src = (isimg ? img : txt) + (size_t)row * DIM;
    float v[3];
    float ss = 0.f;
    #pragma unroll
    for (int i = 0; i < 3; i++){ v[i] = src[threadIdx.x + i*256]; ss += v[i]*v[i]; }
    #pragma unroll
    for (int m = 1; m < 64; m <<= 1) ss += __shfl_xor(ss, m);
    __shared__ float red[4];
    if ((threadIdx.x & 63) == 0) red[threadIdx.x >> 6] = ss;
    __syncthreads();
    float tot = red[0] + red[1] + red[2] + red[3];
    float scale = 1.0f / fmaxf(sqrtf(tot), 1e-12f);
    float* fdst = (isimg ? img_f : txt_f) + (size_t)row * DIM;
    float* odst = (isimg ? out2  : out3 ) + (size_t)row * DIM;
    unsigned short* hid = (isimg ? X2hi : X1hi) + (size_t)row * DIM2;
    unsigned short* lod = (isimg ? X2lo : X1lo) + (size_t)row * DIM2;
    #pragma unroll
    for (int i = 0; i < 3; i++){
        int c = threadIdx.x + i*256;
        float y = v[i] * scale;
        fdst[c] = y; odst[c] = y;
        unsigned short h = f2bf(y);
        hid[c] = h; lod[c] = f2bf(y - bf2f(h));
    }
}

// ---------- transpose W [1536][768] -> Wt [768][1536] (fp32) ----------
__global__ __launch_bounds__(256) void transpose_kernel(
    const float* __restrict__ Wd, const float* __restrict__ Wc,
    float* __restrict__ Td, float* __restrict__ Tc)
{
    __shared__ float t[32][33];
    const float* W = blockIdx.z ? Wc : Wd;
    float*       T = blockIdx.z ? Tc : Td;
    int x0 = blockIdx.x * 32;
    int y0 = blockIdx.y * 32;
    int tx = threadIdx.x & 31, ty = threadIdx.x >> 5;
    #pragma unroll
    for (int i = 0; i < 32; i += 8)
        t[ty + i][tx] = W[(size_t)(y0 + ty + i) * DIM + x0 + tx];
    __syncthreads();
    #pragma unroll
    for (int i = 0; i < 32; i += 8)
        T[(size_t)(x0 + ty + i) * DIM2 + y0 + tx] = t[tx][ty + i];
}

#define EPI_TOP2      0
#define EPI_BIAS_RELU 1
#define EPI_BIAS      2
#define EPI_SCALE     3

// ---------- big GEMM: 8-phase schedule (R7 structure), plain bf16 K64 packing ----------
// BM=BN=256, 8 waves (2M x 4N), per-wave 128x64 output, acc[8][4]. KS=64.
// Row = 128B = [k0..31 | k32..63] as 8 granules of 16B, granule-XOR (row&7) swizzle
// via pre-swizzled global source. Pass Alo = Ahi+32 (same buffer, k32..63).
// LDS: 4 half-tiles x 16KB per K-step, double-buffered = 128 KiB.
// Per K-step kt, 4 phases q: stage {q<2: A_q(kt+1), q>=2: B_(q-2)(kt+2)} || ds_read
// -> s_barrier -> lgkmcnt(0) -> sched_barrier -> setprio(1) -> 16 MFMA (term-loop
// interleaved: same-acc reuse distance 8) -> setprio(0) -> [q==3: vmcnt(4)] -> s_barrier.
// Never drains vmcnt mid-loop (T4). Ledger per R7 (verified): everything K-step kt
// reads was forced complete by vmcnt(4)@(kt-1,3).
template<int EPI>
__global__ __launch_bounds__(512, 2) void gemm_big(
    const unsigned short* __restrict__ Ahi, const unsigned short* __restrict__ Alo, int lda,
    const unsigned short* __restrict__ Bhi, const unsigned short* __restrict__ Blo, int ldb,
    int K, int Nout,
    float* __restrict__ outp, const float* __restrict__ scale_ptr, int Mtot)
{
    constexpr int NT = 512;
    constexpr int KS = 64;
    constexpr int HT = 16384;           // half-tile bytes: 128 rows x 128B
    constexpr int BUF = 4 * HT;         // 64 KiB per K-step
    __shared__ __align__(16) char lds[2 * BUF];   // 128 KiB

    const int tid = threadIdx.x, lane = tid & 63, wid = tid >> 6;
    const int wm = wid >> 2, wn = wid & 3;
    const int lr = lane & 15, lg = lane >> 4;
    // chunked XCD swizzle: 512 blocks -> 64/XCD; (nb, mb) pairs adjacent on one XCD.
    const int id = blockIdx.x;
    const int l  = (id & 7) * 64 + (id >> 3);
    const int nb = l >> 1, mb = l & 1;
    const int m0 = mb * 256, n0 = nb * 256;

    f32x4 acc[8][4] = {};

    // half-tile T: kstep = T>>2, kind = T&3 (0=A0,1=A1,2=B0,3=B1)
    auto stageHT = [&](int T){
        int kind = T & 3, ks = T >> 2;
        char* base = lds + (ks & 1) * BUF + kind * HT;
        const unsigned short* hi = (kind < 2) ? Ahi : Bhi;
        const unsigned short* lo = (kind < 2) ? Alo : Blo;
        int ld = (kind < 2) ? lda : ldb;
        int r0 = ((kind < 2) ? m0 : n0) + (kind & 1) * 128;
        int k0 = ks * KS;
        #pragma unroll
        for (int r = 0; r < 2; r++){
            int G = r * NT + tid, row = G >> 3, slot = G & 7, s0 = slot ^ (row & 7);
            const unsigned short* s = ((s0 < 4) ? hi : lo) + (size_t)(r0 + row) * ld + k0 + (s0 & 3) * 8;
            __builtin_amdgcn_global_load_lds(
                (const __attribute__((address_space(1))) void*)s,
                (__attribute__((address_space(3))) void*)(base + (r * NT + (tid & ~63)) * 16), 16, 0, 0);
        }
    };

    const int xh = (lg ^ (lr & 7)) << 4;        // k0..31 granule byte offset
    const int xl = ((4 + lg) ^ (lr & 7)) << 4;  // k32..63 granule byte offset

    const int nk = K / KS;   // 12
    stageHT(0); stageHT(1); stageHT(2); stageHT(3);
    if (nk > 1){
        stageHT(6); stageHT(7);
        asm volatile("s_waitcnt vmcnt(4)" ::: "memory");
    } else {
        asm volatile("s_waitcnt vmcnt(0)" ::: "memory");
    }
    __syncthreads();

    for (int kt = 0; kt < nk; kt++){
        const char* Ab = lds + (kt & 1) * BUF;
        const char* Bb = Ab + 2 * HT;
        bf16x8 bh[4], bl[4];
        #pragma unroll
        for (int q = 0; q < 4; q++){
            if (q < 2){ if (kt + 1 < nk) stageHT(4 * (kt + 1) + q); }
            else      { if (kt + 2 < nk) stageHT(4 * (kt + 2) + q); }
            if (q == 0){
                #pragma unroll
                for (int nf = 0; nf < 4; nf++){
                    const char* rp = Bb + (wn * 64 + nf * 16 + lr) * 128;
                    bh[nf] = *(const bf16x8*)(rp + xh);
                    bl[nf] = *(const bf16x8*)(rp + xl);
                }
            }
            const char* rp0 = Ab + (wm * 128 + q * 32 + lr) * 128;
            const char* rp1 = rp0 + 16 * 128;
            bf16x8 a0h = *(const bf16x8*)(rp0 + xh);
            bf16x8 a0l = *(const bf16x8*)(rp0 + xl);
            bf16x8 a1h = *(const bf16x8*)(rp1 + xh);
            bf16x8 a1l = *(const bf16x8*)(rp1 + xl);
            asm volatile("s_barrier" ::: "memory");
            asm volatile("s_waitcnt lgkmcnt(0)" ::: "memory");
            __builtin_amdgcn_sched_barrier(0);
            __builtin_amdgcn_s_setprio(1);
            // term-loop outside nf: same-acc reuse distance = 8 MFMAs (no dep stall)
            #pragma unroll
            for (int nf = 0; nf < 4; nf++)
                acc[2*q  ][nf] = __builtin_amdgcn_mfma_f32_16x16x32_bf16(a0h, bh[nf], acc[2*q  ][nf], 0, 0, 0);
            #pragma unroll
            for (int nf = 0; nf < 4; nf++)
                acc[2*q+1][nf] = __builtin_amdgcn_mfma_f32_16x16x32_bf16(a1h, bh[nf], acc[2*q+1][nf], 0, 0, 0);
            #pragma unroll
            for (int nf = 0; nf < 4; nf++)
                acc[2*q  ][nf] = __builtin_amdgcn_mfma_f32_16x16x32_bf16(a0l, bl[nf], acc[2*q  ][nf], 0, 0, 0);
            #pragma unroll
            for (int nf = 0; nf < 4; nf++)
                acc[2*q+1][nf] = __builtin_amdgcn_mfma_f32_16x16x32_bf16(a1l, bl[nf], acc[2*q+1][nf], 0, 0, 0);
            __builtin_amdgcn_s_setprio(0);
            if (q == 3){
                if (kt < nk - 2)       asm volatile("s_waitcnt vmcnt(4)" ::: "memory");
                else if (kt == nk - 2) asm volatile("s_waitcnt vmcnt(0)" ::: "memory");
            }
            asm volatile("s_barrier" ::: "memory");
        }
    }

    if constexpr (EPI == EPI_TOP2){
        T2* t2l = (T2*)lds;   // [4][256]
        #pragma unroll
        for (int mf = 0; mf < 8; mf++){
            #pragma unroll
            for (int r = 0; r < 4; r++){
                T2 t = t2_init();
                #pragma unroll
                for (int nf = 0; nf < 4; nf++){
                    int gc = n0 + wn * 64 + nf * 16 + lr;
                    t2_add(t, acc[mf][nf][r], gc);
                }
                #pragma unroll
                for (int m = 1; m < 16; m <<= 1){
                    float ov1 = __shfl_xor(t.v1, m), ov2 = __shfl_xor(t.v2, m);
                    int   oi1 = __shfl_xor(t.i1, m), oi2 = __shfl_xor(t.i2, m);
                    t2_add(t, ov1, oi1); t2_add(t, ov2, oi2);
                }
                if (lr == 0){
                    int rowit = wm * 128 + mf * 16 + lg * 4 + r;
                    t2l[wn * 256 + rowit] = t;
                }
            }
        }
        __syncthreads();
        if (tid < 256){
            T2 t = t2l[tid];
            #pragma unroll
            for (int w = 1; w < 4; w++){
                T2 o = t2l[w * 256 + tid];
                t2_add(t, o.v1, o.i1); t2_add(t, o.v2, o.i2);
            }
            f32x4 pk; pk[0] = t.v1; pk[1] = __int_as_float(t.i1); pk[2] = t.v2; pk[3] = __int_as_float(t.i2);
            ((f32x4*)outp)[(size_t)nb * Mtot + (m0 + tid)] = pk;
        }
    } else if constexpr (EPI == EPI_SCALE){
        float sc = scale_ptr[0];
        #pragma unroll
        for (int mf = 0; mf < 8; mf++)
        #pragma unroll
        for (int nf = 0; nf < 4; nf++)
        #pragma unroll
        for (int r = 0; r < 4; r++){
            int grow = m0 + wm * 128 + mf * 16 + lg * 4 + r;
            int gcol = n0 + wn * 64 + nf * 16 + lr;
            outp[(size_t)grow * Nout + gcol] = acc[mf][nf][r] * sc;
        }
    }
}

// ---------- small GEMM (MLP layers): A bf16 hi/lo, B fp32 with in-kernel convert ----------
template<int BM,int BN,int WGM,int WGN,int EPI>
__global__ __launch_bounds__(WGM*WGN*64) void gemm_small(
    const unsigned short* __restrict__ Ahi, const unsigned short* __restrict__ Alo, int lda,
    const float* __restrict__ B, int ldb, int K,
    const float* __restrict__ bias,
    unsigned short* __restrict__ dsthi, unsigned short* __restrict__ dstlo, int ldd, int dstoff)
{
    constexpr int WM = BM / WGM, WN = BN / WGN;
    constexpr int MF = WM / 16, NF = WN / 16;
    constexpr int NT = WGM * WGN * 64;
    constexpr int ABYTES = BM * 128;
    constexpr int BBYTES = BN * 128;
    constexpr int BUF = ABYTES + BBYTES;
    static_assert(BN * 4 == NT, "");
    static_assert((BM * 8) % NT == 0, "");

    __shared__ __align__(16) char lds[2 * BUF];

    const int tid  = threadIdx.x;
    const int wid  = tid >> 6, lane = tid & 63;
    const int wm   = wid / WGN, wn = wid % WGN;
    const int lr   = lane & 15, lg = lane >> 4;
    const int nb   = blockIdx.x, mb = blockIdx.y;
    const int m0   = mb * BM, n0 = nb * BN;

    f32x4 acc[MF][NF] = {};
    f32x4 breg0, breg1;

    auto stageA = [&](int buf, int k0){
        char* base = lds + buf * BUF;
        constexpr int RA = BM * 8 / NT;
        #pragma unroll
        for (int r = 0; r < RA; r++){
            int G = r * NT + tid;
            int row = G >> 3, slot = G & 7;
            int s0 = slot ^ (row & 7);
            const unsigned short* src = ((s0 < 4) ? Ahi : Alo)
                + (size_t)(m0 + row) * lda + (k0 + (s0 & 3) * 8);
            char* ldst = base + r * NT * 16 + (tid & ~63) * 16;
            __builtin_amdgcn_global_load_lds(
                (const __attribute__((address_space(1))) void*)src,
                (__attribute__((address_space(3))) void*)ldst, 16, 0, 0);
        }
    };
    auto loadB = [&](int kt){
        int k0 = kt * 32;
        int row = tid >> 2, quad = tid & 3;
        const float* bp = B + (size_t)(n0 + row) * ldb + k0 + quad * 8;
        breg0 = *(const f32x4*)bp;
        breg1 = *(const f32x4*)(bp + 4);
    };
    auto writeB = [&](int buf){
        char* base = lds + buf * BUF + ABYTES;
        int row = tid >> 2, quad = tid & 3;
        u16x8 h8, l8;
        #pragma unroll
        for (int j = 0; j < 8; j++){
            float x = (j < 4) ? breg0[j] : breg1[j - 4];
            unsigned short h = f2bf(x);
            h8[j] = h; l8[j] = f2bf(x - bf2f(h));
        }
        int sh = quad ^ (row & 7), sl = (4 + quad) ^ (row & 7);
        *(u16x8*)(base + row * 128 + sh * 16) = h8;
        *(u16x8*)(base + row * 128 + sl * 16) = l8;
    };
    auto compute = [&](int buf){
        const char* Ab = lds + buf * BUF;
        const char* Bb = Ab + ABYTES;
        bf16x8 ah[MF], al[MF], bh[NF], bl[NF];
        #pragma unroll
        for (int mf = 0; mf < MF; mf++){
            int row = wm * WM + mf * 16 + lr;
            const char* rp = Ab + row * 128;
            ah[mf] = *(const bf16x8*)(rp + ((lg ^ (row & 7)) << 4));
            al[mf] = *(const bf16x8*)(rp + (((4 + lg) ^ (row & 7)) << 4));
        }
        #pragma unroll
        for (int nf = 0; nf < NF; nf++){
            int row = wn * WN + nf * 16 + lr;
            const char* rp = Bb + row * 128;
            bh[nf] = *(const bf16x8*)(rp + ((lg ^ (row & 7)) << 4));
            bl[nf] = *(const bf16x8*)(rp + (((4 + lg) ^ (row & 7)) << 4));
        }
        #pragma unroll
        for (int mf = 0; mf < MF; mf++)
        #pragma unroll
        for (int nf = 0; nf < NF; nf++){
            acc[mf][nf] = __builtin_amdgcn_mfma_f32_16x16x32_bf16(ah[mf], bh[nf], acc[mf][nf], 0, 0, 0);
            acc[mf][nf] = __builtin_amdgcn_mfma_f32_16x16x32_bf16(al[mf], bh[nf], acc[mf][nf], 0, 0, 0);
            acc[mf][nf] = __builtin_amdgcn_mfma_f32_16x16x32_bf16(ah[mf], bl[nf], acc[mf][nf], 0, 0, 0);
        }
    };

    stageA(0, 0); loadB(0); writeB(0);
    __syncthreads();
    const int nk = K / 32;
    int cur = 0;
    for (int kt = 0; kt < nk; kt++){
        if (kt + 1 < nk){ stageA(cur ^ 1, (kt + 1) * 32); loadB(kt + 1); }
        compute(cur);
        if (kt + 1 < nk){ writeB(cur ^ 1); }
        __syncthreads();
        cur ^= 1;
    }

    #pragma unroll
    for (int mf = 0; mf < MF; mf++)
    #pragma unroll
    for (int nf = 0; nf < NF; nf++)
    #pragma unroll
    for (int r = 0; r < 4; r++){
        int grow = m0 + wm * WM + mf * 16 + lg * 4 + r;
        int gcol = n0 + wn * WN + nf * 16 + lr;
        float c = acc[mf][nf][r] + bias[gcol];
        if (EPI == EPI_BIAS_RELU) c = fmaxf(c, 0.f);
        unsigned short h = f2bf(c);
        size_t o = (size_t)grow * ldd + dstoff + gcol;
        dsthi[o] = h;
        dstlo[o] = f2bf(c - bf2f(h));
    }
}

// ---------- phase B: global top-4 from per-tile top-2s + exact fp32 rescore ----------
// One 256-thread block per row. 512 candidate entries (256 tiles x top-2) -> 4 sweeps of
// block-argmax (mask selected index) -> exact fp32 dot for each of the 4 -> argmax with
// lowest-index tiebreak (matches jnp.argmax first-occurrence semantics).
__global__ __launch_bounds__(256) void phaseB_kernel(
    const f32x4* __restrict__ top2ws, int ntiles,
    const float* __restrict__ img_f, const float* __restrict__ qtxt,
    float* __restrict__ out_ind, int* __restrict__ ws_ind)
{
    __shared__ float vals[512];
    __shared__ int   inds[512];
    __shared__ float red[4];
    __shared__ int   redi[4];
    __shared__ int   cands[4];
    __shared__ float cscore[4];
    const int row = blockIdx.x, tid = threadIdx.x;

    if (tid < ntiles){
        f32x4 e = top2ws[(size_t)tid * BATCH + row];
        vals[2*tid]   = e[0]; inds[2*tid]   = __float_as_int(e[1]);
        vals[2*tid+1] = e[2]; inds[2*tid+1] = __float_as_int(e[3]);
    }
    __syncthreads();

    for (int it = 0; it < 4; it++){
        float v = vals[tid]; int i = inds[tid];
        {
            float v2 = vals[tid+256]; int i2 = inds[tid+256];
            if (v2 > v || (v2 == v && i2 < i)){ v = v2; i = i2; }
        }
        #pragma unroll
        for (int m = 1; m < 64; m <<= 1){
            float ov = __shfl_xor(v, m); int oi = __shfl_xor(i, m);
            if (ov > v || (ov == v && oi < i)){ v = ov; i = oi; }
        }
        if ((tid & 63) == 0){ red[tid>>6] = v; redi[tid>>6] = i; }
        __syncthreads();
        if (tid == 0){
            float bv = red[0]; int bi = redi[0];
            #pragma unroll
            for (int w = 1; w < 4; w++)
                if (red[w] > bv || (red[w] == bv && redi[w] < bi)){ bv = red[w]; bi = redi[w]; }
            cands[it] = bi;
        }
        __syncthreads();
        if (inds[tid]     == cands[it]) vals[tid]     = -3.4e38f;
        if (inds[tid+256] == cands[it]) vals[tid+256] = -3.4e38f;
        __syncthreads();
    }

    // exact fp32 rescore of the 4 candidates
    const float* a = img_f + (size_t)row * DIM;
    float a0 = a[tid], a1 = a[tid + 256], a2 = a[tid + 512];
    for (int c = 0; c < 4; c++){
        const float* b = qtxt + (size_t)cands[c] * DIM;
        float s = a0 * b[tid] + a1 * b[tid + 256] + a2 * b[tid + 512];
        #pragma unroll
        for (int m = 1; m < 64; m <<= 1) s += __shfl_xor(s, m);
        if ((tid & 63) == 0) red[tid>>6] = s;
        __syncthreads();
        if (tid == 0) cscore[c] = red[0] + red[1] + red[2] + red[3];
        __syncthreads();
    }
    if (tid == 0){
        float bs = cscore[0]; int bi = cands[0];
        #pragma unroll
        for (int c = 1; c < 4; c++)
            if (cscore[c] > bs || (cscore[c] == bs && cands[c] < bi)){ bs = cscore[c]; bi = cands[c]; }
        out_ind[row] = (float)bi; ws_ind[row] = bi;
    }
}

// ---------- gather t_similar rows into X1[:, 768:1536] as bf16 hi/lo ----------
__global__ __launch_bounds__(256) void gather_kernel(
    const int* __restrict__ ws_ind, const float* __restrict__ qtxt,
    unsigned short* __restrict__ X1hi, unsigned short* __restrict__ X1lo)
{
    int row = blockIdx.x;
    int ind = ws_ind[row];
    const float* src = qtxt + (size_t)ind * DIM;
    for (int c = threadIdx.x; c < DIM; c += 256){
        float x = src[c];
        unsigned short h = f2bf(x);
        X1hi[(size_t)row * DIM2 + DIM + c] = h;
        X1lo[(size_t)row * DIM2 + DIM + c] = f2bf(x - bf2f(h));
    }
}

extern "C" void kernel_launch(void* const* d_in, const int* in_sizes, int n_in,
                              void* d_out, int out_size, void* d_ws, size_t ws_size,
                              hipStream_t stream)
{
    (void)in_sizes; (void)n_in; (void)out_size; (void)ws_size;
    const float* img  = (const float*)d_in[0];
    const float* txt  = (const float*)d_in[1];
    const float* qimg = (const float*)d_in[2];
    const float* qtxt = (const float*)d_in[3];
    const float* Wd   = (const float*)d_in[4];
    const float* bd   = (const float*)d_in[5];
    const float* Wc   = (const float*)d_in[6];
    const float* bc   = (const float*)d_in[7];
    const float* ls   = (const float*)d_in[8];

    float* out0 = (float*)d_out;                    // logits [512][65536]
    float* out1 = out0 + (size_t)BATCH * NQ;        // ind_similar [512] (as f32)
    float* out2 = out1 + BATCH;                     // new_queue_img [65536][768]
    float* out3 = out2 + (size_t)NQ * DIM;          // new_queue_txt [65536][768]

    char* w = (char*)d_ws;
    auto alloc = [&](size_t bytes){ char* p = w; w += (bytes + 255) & ~(size_t)255; return p; };
    unsigned short* X1hi  = (unsigned short*)alloc((size_t)BATCH * DIM2 * 2);
    unsigned short* X1lo  = (unsigned short*)alloc((size_t)BATCH * DIM2 * 2);
    unsigned short* X2hi  = (unsigned short*)alloc((size_t)BATCH * DIM2 * 2);
    unsigned short* X2lo  = (unsigned short*)alloc((size_t)BATCH * DIM2 * 2);
    unsigned short* combhi= (unsigned short*)alloc((size_t)BATCH * DIM * 2);
    unsigned short* comblo= (unsigned short*)alloc((size_t)BATCH * DIM * 2);
    float* img_f  = (float*)alloc((size_t)BATCH * DIM * 4);
    float* txt_f  = (float*)alloc((size_t)BATCH * DIM * 4);
    float* Td     = (float*)alloc((size_t)DIM * DIM2 * 4);
    float* Tc     = (float*)alloc((size_t)DIM * DIM2 * 4);
    float* top2ws = (float*)alloc((size_t)(NQ / 256) * BATCH * 16);
    int*   ws_ind = (int*)alloc(BATCH * 4);
    unsigned short* Bt_hi = (unsigned short*)alloc((size_t)NQ * DIM * 2);
    unsigned short* Bi_hi = (unsigned short*)alloc((size_t)NQ * DIM * 2);

    // 1) convert queues to bf16 (hi only) + fp32 passthrough into out2/out3
    convert_kernel<<<dim3(2048, 2), dim3(256), 0, stream>>>(
        qtxt, qimg, Bt_hi, Bi_hi, out3, out2);

    // 2) normalize features (overwrites out2/out3 rows 0..511), split to hi/lo
    prep_kernel<<<dim3(2 * BATCH), dim3(256), 0, stream>>>(
        img, txt, img_f, txt_f, X2hi, X2lo, X1hi, X1lo, out2, out3);

    // 3) transpose weights to [768][1536] fp32
    transpose_kernel<<<dim3(DIM / 32, DIM2 / 32, 2), dim3(256), 0, stream>>>(Wd, Wc, Td, Tc);

    // 4) retrieval GEMM: plain bf16 hi-only (K64 packing) + per-tile top2  [512 blocks]
    gemm_big<EPI_TOP2><<<dim3(512), dim3(512), 0, stream>>>(
        X2hi, X2hi + 32, DIM2, Bt_hi, Bt_hi + 32, DIM, DIM, NQ, top2ws, nullptr, BATCH);

    // 5) global top-4 + exact fp32 rescore -> ind_similar
    phaseB_kernel<<<dim3(BATCH), dim3(256), 0, stream>>>(
        (const f32x4*)top2ws, NQ / 256, img_f, qtxt, out1, ws_ind);

    // 6) gather t_similar into X1[:, 768:]
    gather_kernel<<<dim3(BATCH), dim3(256), 0, stream>>>(ws_ind, qtxt, X1hi, X1lo);

    // 7) diff = relu(X1 @ W_diff + b_diff) -> X2[:, 768:] (split)
    gemm_small<64,64,2,2,EPI_BIAS_RELU><<<dim3(DIM / 64, BATCH / 64), dim3(256), 0, stream>>>(
        X1hi, X1lo, DIM2, Td, DIM2, DIM2, bd, X2hi, X2lo, DIM2, DIM);

    // 8) combined = X2 @ W_comb + b_comb -> comb hi/lo
    gemm_small<64,64,2,2,EPI_BIAS><<<dim3(DIM / 64, BATCH / 64), dim3(256), 0, stream>>>(
        X2hi, X2lo, DIM2, Tc, DIM2, DIM2, bc, combhi, comblo, DIM, 0);

    // 9) logits = scale * combined @ queue_img^T (K64 hi-only, 8-phase)  [512 blocks]
    gemm_big<EPI_SCALE><<<dim3(512), dim3(512), 0, stream>>>(
        combhi, combhi + 32, DIM, Bi_hi, Bi_hi + 32, DIM, DIM, NQ, out0, ls, BATCH);
}